// Round 14
// baseline (1053.687 us; speedup 1.0000x reference)
//
#include <hip/hip_runtime.h>

// R14: pair_mlp LDS XOR-swizzle (T2): stride 264->256, ushort idx ^= (row&7)<<3
// on ah/al/w3s for all readers+writers. Kills the lane=row bank aliasing that
// R13 doubled (conflicts 2.1e7->4.2e7 with 2x waves). Pure layout change,
// numerics identical. R13 audit: LDS pipe ~16k of 24.9k cyc/group is the cap.
#define N_DETS 16384
#define DEG 32
#define E_EDGES (N_DETS * DEG)   // 524288
#define EDGE_GRID 512

typedef __attribute__((ext_vector_type(8))) short bf16x8;
typedef __attribute__((ext_vector_type(4))) float f32x4;

__device__ __forceinline__ ushort f32_to_bf16(float v) {
  unsigned u = __float_as_uint(v);
  u += 0x7FFFu + ((u >> 16) & 1u);    // round-to-nearest-even
  return (ushort)(u >> 16);
}
__device__ __forceinline__ float bf16_to_f32(ushort h) {
  return __uint_as_float((unsigned)h << 16);
}

// ============ prep: out[n][k] = split_hi/lo(W[k][n]); K==256, grid=N ============
__global__ __launch_bounds__(256) void split_w_kernel(
    const float* __restrict__ W, ushort* __restrict__ hi, ushort* __restrict__ lo, int N)
{
  const int n = blockIdx.x, k = threadIdx.x;
  const float v = W[(size_t)k * N + n];
  const ushort h = f32_to_bf16(v);
  const ushort l = f32_to_bf16(v - bf16_to_f32(h));
  hi[(size_t)n * 256 + k] = h;
  lo[(size_t)n * 256 + k] = l;
}

// ============ prep: edge-block W1 (96x64) + W2 (64x64) -> [col][k] split ============
__global__ __launch_bounds__(256) void split_edge_w_kernel(
    const float* __restrict__ W1all, const float* __restrict__ W2all,
    ushort* __restrict__ w1h, ushort* __restrict__ w1l,
    ushort* __restrict__ w2h, ushort* __restrict__ w2l)
{
  const int b = blockIdx.x;
  const float* W1 = W1all + b * 6144;
  const float* W2 = W2all + b * 4096;
  for (int i = threadIdx.x; i < 6144; i += 256) {
    const int col = i / 96, k = i % 96;
    const float v = W1[k * 64 + col];
    const ushort h = f32_to_bf16(v);
    w1h[b * 6144 + col * 96 + k] = h;
    w1l[b * 6144 + col * 96 + k] = f32_to_bf16(v - bf16_to_f32(h));
  }
  for (int i = threadIdx.x; i < 4096; i += 256) {
    const int col = i >> 6, k = i & 63;
    const float v = W2[k * 64 + col];
    const ushort h = f32_to_bf16(v);
    w2h[b * 4096 + col * 64 + k] = h;
    w2l[b * 4096 + col * 64 + k] = f32_to_bf16(v - bf16_to_f32(h));
  }
}

// ===================== pairwise MLP: 9 -> 256 -> 256 -> 32 =====================
// Swizzled LDS: element (row, c) lives at row*256 + (c ^ ((row&7)<<3)) ushorts.
#define SWZ(row, c) ((c) ^ (((row) & 7) << 3))

__global__ __launch_bounds__(1024, 4) void pair_mlp_kernel(
    const float* __restrict__ raw,
    const float* __restrict__ W1, const float* __restrict__ b1,
    const ushort* __restrict__ w2h, const ushort* __restrict__ w2l,
    const float* __restrict__ b2,
    const ushort* __restrict__ w3h, const ushort* __restrict__ w3l,
    const float* __restrict__ b3,
    ushort* __restrict__ pair_h, ushort* __restrict__ pair_l)
{
  __shared__ __align__(16) ushort ah[64 * 256];    // 32 KB (h1 then h2), swizzled
  __shared__ __align__(16) ushort al[64 * 256];    // 32 KB, swizzled
  __shared__ __align__(16) ushort w3sh[32 * 256];  // 16 KB, swizzled
  __shared__ __align__(16) ushort w3sl[32 * 256];  // 16 KB, swizzled
  __shared__ __align__(16) float rawt[64 * 12];    // 3 KB  => 99 KB total

  const int t = threadIdx.x;
  const int lane = t & 63, wv = t >> 6;    // 16 waves
  const int ln = lane & 15, kg = lane >> 4;

  // one-time: stage W3 split into swizzled LDS
  for (int i = t; i < 32 * 64; i += 1024) {
    const int row = (i * 4) >> 8, col = (i * 4) & 255;
    const int sidx = row * 256 + SWZ(row, col);   // col mult of 4, swz mult of 8
    *(ushort4*)&w3sh[sidx] = *(const ushort4*)&w3h[row * 256 + col];
    *(ushort4*)&w3sl[sidx] = *(const ushort4*)&w3l[row * 256 + col];
  }

  // one-time: W2 split fragments -> registers (wave wv owns cols 16wv..16wv+15)
  bf16x8 b2hreg[8], b2lreg[8];
  #pragma unroll
  for (int ks = 0; ks < 8; ++ks) {
    const size_t bo = (size_t)(wv * 16 + ln) * 256 + ks * 32 + kg * 8;
    b2hreg[ks] = *(const bf16x8*)&w2h[bo];
    b2lreg[ks] = *(const bf16x8*)&w2l[bo];
  }
  const float bias2 = b2[wv * 16 + ln];
  const int mt3 = (wv >> 1) & 3, nt3 = wv & 1;
  const float b3v = b3[nt3 * 16 + ln];
  __syncthreads();   // w3 staging visible

  for (int grp = blockIdx.x; grp < E_EDGES / 64; grp += gridDim.x) {
    const long long e0 = (long long)grp * 64;

    if (t < 64 * 9) rawt[(t / 9) * 12 + (t % 9)] = raw[e0 * 9 + t];
    __syncthreads();

    // ---- layer 1: thread owns col (t&255), rows (t>>8)*16..+16 ----
    {
      const int col = t & 255, r0 = (t >> 8) * 16;
      const float bv = b1[col];
      float wk[9];
      #pragma unroll
      for (int k = 0; k < 9; ++k) wk[k] = W1[k * 256 + col];
      #pragma unroll
      for (int r = 0; r < 16; ++r) {
        const int row = r0 + r;
        const float4 ra = *(const float4*)&rawt[row * 12];
        const float4 rb = *(const float4*)&rawt[row * 12 + 4];
        const float rc = rawt[row * 12 + 8];
        float s = bv;
        s = fmaf(ra.x, wk[0], s); s = fmaf(ra.y, wk[1], s);
        s = fmaf(ra.z, wk[2], s); s = fmaf(ra.w, wk[3], s);
        s = fmaf(rb.x, wk[4], s); s = fmaf(rb.y, wk[5], s);
        s = fmaf(rb.z, wk[6], s); s = fmaf(rb.w, wk[7], s);
        s = fmaf(rc, wk[8], s);
        const float v = fmaxf(s, 0.f);
        const ushort h = f32_to_bf16(v);
        const int sidx = row * 256 + SWZ(row, col);
        ah[sidx] = h;
        al[sidx] = f32_to_bf16(v - bf16_to_f32(h));
      }
    }
    __syncthreads();

    // ---- layer 2 K-loop: LDS A (swizzled) + resident-B MFMA (wave owns 16 cols) ----
    f32x4 acc[4];
    #pragma unroll
    for (int mt = 0; mt < 4; ++mt) {
      acc[mt][0] = 0.f; acc[mt][1] = 0.f; acc[mt][2] = 0.f; acc[mt][3] = 0.f;
    }
    const int lswz = (ln & 7) << 3;
    #pragma unroll
    for (int ks = 0; ks < 8; ++ks) {
      const int ka = (ks * 32 + kg * 8) ^ lswz;   // row&7 == ln&7 for rows mt*16+ln
      #pragma unroll
      for (int mt = 0; mt < 4; ++mt) {
        const bf16x8 ahf = *(const bf16x8*)&ah[(mt * 16 + ln) * 256 + ka];
        const bf16x8 alf = *(const bf16x8*)&al[(mt * 16 + ln) * 256 + ka];
        acc[mt] = __builtin_amdgcn_mfma_f32_16x16x32_bf16(ahf, b2hreg[ks], acc[mt], 0, 0, 0);
        acc[mt] = __builtin_amdgcn_mfma_f32_16x16x32_bf16(alf, b2hreg[ks], acc[mt], 0, 0, 0);
        acc[mt] = __builtin_amdgcn_mfma_f32_16x16x32_bf16(ahf, b2lreg[ks], acc[mt], 0, 0, 0);
      }
    }
    __syncthreads();   // all reads of h1 complete

    // ---- epilogue: +b2, relu, re-split into ah/al (h2, swizzled) ----
    {
      const int colg = wv * 16 + ln;
      #pragma unroll
      for (int mt = 0; mt < 4; ++mt)
        #pragma unroll
        for (int r = 0; r < 4; ++r) {
          const int rowe = mt * 16 + kg * 4 + r;
          const float v = fmaxf(acc[mt][r] + bias2, 0.f);
          const ushort h = f32_to_bf16(v);
          const int sidx = rowe * 256 + SWZ(rowe, colg);
          ah[sidx] = h;
          al[sidx] = f32_to_bf16(v - bf16_to_f32(h));
        }
    }
    __syncthreads();

    // ---- layer 3 (waves 0-7): wave -> (mt3, nt3) tile; B from swizzled LDS ----
    if (wv < 8) {
      f32x4 acc3;
      acc3[0] = 0.f; acc3[1] = 0.f; acc3[2] = 0.f; acc3[3] = 0.f;
      #pragma unroll
      for (int ks = 0; ks < 8; ++ks) {
        const int ka = (ks * 32 + kg * 8) ^ lswz;   // rows mt3*16+ln / nt3*16+ln: row&7==ln&7
        const bf16x8 a_h = *(const bf16x8*)&ah[(mt3 * 16 + ln) * 256 + ka];
        const bf16x8 a_l = *(const bf16x8*)&al[(mt3 * 16 + ln) * 256 + ka];
        const bf16x8 b_h = *(const bf16x8*)&w3sh[(nt3 * 16 + ln) * 256 + ka];
        const bf16x8 b_l = *(const bf16x8*)&w3sl[(nt3 * 16 + ln) * 256 + ka];
        acc3 = __builtin_amdgcn_mfma_f32_16x16x32_bf16(a_h, b_h, acc3, 0, 0, 0);
        acc3 = __builtin_amdgcn_mfma_f32_16x16x32_bf16(a_l, b_h, acc3, 0, 0, 0);
        acc3 = __builtin_amdgcn_mfma_f32_16x16x32_bf16(a_h, b_l, acc3, 0, 0, 0);
      }
      const int col3 = nt3 * 16 + ln;
      #pragma unroll
      for (int r = 0; r < 4; ++r) {
        const int rowe = mt3 * 16 + kg * 4 + r;
        const float v = fmaxf(acc3[r] + b3v, 0.f);
        const ushort h = f32_to_bf16(v);
        const size_t idx = (size_t)(e0 + rowe) * 32 + col3;
        pair_h[idx] = h;
        pair_l[idx] = f32_to_bf16(v - bf16_to_f32(h));
      }
    }
    __syncthreads();   // L3 reads done before next iter's L1 overwrites ah/al
  }
}

// ========== f = relu(x @ fc1_W + b) : (N,128)@(128,32); emits f32 + split ==========
__global__ __launch_bounds__(256) void fc1_kernel(
    const float* __restrict__ x, const float* __restrict__ W,
    const float* __restrict__ b, float* __restrict__ f,
    ushort* __restrict__ f_h, ushort* __restrict__ f_l)
{
  __shared__ float Wl[128 * 32];
  const int t = threadIdx.x;
  #pragma unroll
  for (int j = 0; j < 4; ++j) {
    const int off = t * 4 + j * 1024;
    *(float4*)&Wl[off] = *(const float4*)&W[off];
  }
  __syncthreads();
  const int c = t & 31, rr = t >> 5;
  const long long r = (long long)blockIdx.x * 8 + rr;
  const float* xr = x + r * 128;
  float acc = b[c];
  #pragma unroll 8
  for (int k = 0; k < 128; k += 4) {
    const float4 a = *(const float4*)&xr[k];
    acc = fmaf(a.x, Wl[(k + 0) * 32 + c], acc);
    acc = fmaf(a.y, Wl[(k + 1) * 32 + c], acc);
    acc = fmaf(a.z, Wl[(k + 2) * 32 + c], acc);
    acc = fmaf(a.w, Wl[(k + 3) * 32 + c], acc);
  }
  const float v = fmaxf(acc, 0.f);
  f[r * 32 + c] = v;
  const ushort h = f32_to_bf16(v);
  f_h[r * 32 + c] = h;
  f_l[r * 32 + c] = f32_to_bf16(v - bf16_to_f32(h));
}

// ====== edge MLP (96->64->64) + segment-max, split-bf16 MFMA, persistent ======
#define W1S 104
#define W2S 72
#define CTS 36

__global__ __launch_bounds__(512, 2) void edge_kernel(
    const ushort* __restrict__ pair_h, const ushort* __restrict__ pair_l,
    const float* __restrict__ f,
    const ushort* __restrict__ f_h, const ushort* __restrict__ f_l,
    const int* __restrict__ nIdxs,
    const float* __restrict__ W1g, const float* __restrict__ bb1,
    const ushort* __restrict__ gw1h, const ushort* __restrict__ gw1l,
    const ushort* __restrict__ gw2h, const ushort* __restrict__ gw2l,
    const float* __restrict__ bb2,
    float* __restrict__ m)
{
  __shared__ __align__(16) ushort W1hS[64 * W1S], W1lS[64 * W1S];
  __shared__ __align__(16) ushort W2hS[64 * W2S], W2lS[64 * W2S];
  __shared__ __align__(16) float  W1cT[64 * CTS];
  __shared__ __align__(16) ushort h1h[8][32 * W2S], h1l[8][32 * W2S];

  const int t = threadIdx.x;
  const int lane = t & 63, wv = t >> 6;
  const int ln = lane & 15, kg = lane >> 4;

  // ---- one-time: stage weight tables ----
  for (int i = t; i < 1536; i += 512) {
    const int idx = i * 4, row = idx / 96, k = idx % 96;
    *(ushort4*)&W1hS[row * W1S + k] = *(const ushort4*)&gw1h[idx];
    *(ushort4*)&W1lS[row * W1S + k] = *(const ushort4*)&gw1l[idx];
  }
  for (int i = t; i < 1024; i += 512) {
    const int idx = i * 4, row = idx >> 6, k = idx & 63;
    *(ushort4*)&W2hS[row * W2S + k] = *(const ushort4*)&gw2h[idx];
    *(ushort4*)&W2lS[row * W2S + k] = *(const ushort4*)&gw2l[idx];
  }
  for (int i = t; i < 2048; i += 512) {
    const int col = i >> 5, j = i & 31;
    W1cT[col * CTS + j] = W1g[(32 + j) * 64 + col];
  }
  __syncthreads();

  // ---- persistent loop over det-groups; no barriers inside (h1 per-wave) ----
  for (int dg = blockIdx.x; dg < N_DETS / 8; dg += gridDim.x) {
    const int d = dg * 8 + wv;
    const long long e0 = (long long)d * 32;

    float cfs[4];
    {
      const float4 fv0 = *(const float4*)&f[(size_t)d * 32 + kg * 8];
      const float4 fv1 = *(const float4*)&f[(size_t)d * 32 + kg * 8 + 4];
      #pragma unroll
      for (int nt = 0; nt < 4; ++nt) {
        const int col = nt * 16 + ln;
        const float4 w0 = *(const float4*)&W1cT[col * CTS + kg * 8];
        const float4 w1 = *(const float4*)&W1cT[col * CTS + kg * 8 + 4];
        float s = fv0.x * w0.x + fv0.y * w0.y + fv0.z * w0.z + fv0.w * w0.w
                + fv1.x * w1.x + fv1.y * w1.y + fv1.z * w1.z + fv1.w * w1.w;
        s += __shfl_xor(s, 16);
        s += __shfl_xor(s, 32);
        cfs[nt] = s + bb1[col];
      }
    }

    f32x4 acc1[4][2];
    #pragma unroll
    for (int nt = 0; nt < 4; ++nt)
      #pragma unroll
      for (int mt = 0; mt < 2; ++mt) {
        acc1[nt][mt][0] = 0.f; acc1[nt][mt][1] = 0.f;
        acc1[nt][mt][2] = 0.f; acc1[nt][mt][3] = 0.f;
      }
    bf16x8 ph[2], pl_[2], nh[2], nl_[2];
    #pragma unroll
    for (int mt = 0; mt < 2; ++mt) {
      const long long row = e0 + mt * 16 + ln;
      ph[mt]  = *(const bf16x8*)&pair_h[row * 32 + kg * 8];
      pl_[mt] = *(const bf16x8*)&pair_l[row * 32 + kg * 8];
      const int n = nIdxs[row];
      bf16x8 vh = *(const bf16x8*)&f_h[(size_t)n * 32 + kg * 8];
      bf16x8 vl = *(const bf16x8*)&f_l[(size_t)n * 32 + kg * 8];
      if (n == d) { vh = (bf16x8){0,0,0,0,0,0,0,0}; vl = (bf16x8){0,0,0,0,0,0,0,0}; }
      nh[mt] = vh; nl_[mt] = vl;
    }
    #pragma unroll
    for (int nt = 0; nt < 4; ++nt) {
      const int bro = (nt * 16 + ln) * W1S;
      const bf16x8 b0h = *(const bf16x8*)&W1hS[bro + kg * 8];
      const bf16x8 b0l = *(const bf16x8*)&W1lS[bro + kg * 8];
      const bf16x8 b1h = *(const bf16x8*)&W1hS[bro + 64 + kg * 8];
      const bf16x8 b1l = *(const bf16x8*)&W1lS[bro + 64 + kg * 8];
      #pragma unroll
      for (int mt = 0; mt < 2; ++mt) {
        acc1[nt][mt] = __builtin_amdgcn_mfma_f32_16x16x32_bf16(ph[mt], b0h, acc1[nt][mt], 0, 0, 0);
        acc1[nt][mt] = __builtin_amdgcn_mfma_f32_16x16x32_bf16(pl_[mt], b0h, acc1[nt][mt], 0, 0, 0);
        acc1[nt][mt] = __builtin_amdgcn_mfma_f32_16x16x32_bf16(ph[mt], b0l, acc1[nt][mt], 0, 0, 0);
        acc1[nt][mt] = __builtin_amdgcn_mfma_f32_16x16x32_bf16(nh[mt], b1h, acc1[nt][mt], 0, 0, 0);
        acc1[nt][mt] = __builtin_amdgcn_mfma_f32_16x16x32_bf16(nl_[mt], b1h, acc1[nt][mt], 0, 0, 0);
        acc1[nt][mt] = __builtin_amdgcn_mfma_f32_16x16x32_bf16(nh[mt], b1l, acc1[nt][mt], 0, 0, 0);
      }
    }

    #pragma unroll
    for (int nt = 0; nt < 4; ++nt) {
      const int col = nt * 16 + ln;
      #pragma unroll
      for (int mt = 0; mt < 2; ++mt)
        #pragma unroll
        for (int r = 0; r < 4; ++r) {
          const int row = mt * 16 + kg * 4 + r;
          const float v = fmaxf(acc1[nt][mt][r] + cfs[nt], 0.f);
          const ushort h = f32_to_bf16(v);
          h1h[wv][row * W2S + col] = h;
          h1l[wv][row * W2S + col] = f32_to_bf16(v - bf16_to_f32(h));
        }
    }

    f32x4 acc2[4][2];
    #pragma unroll
    for (int mt = 0; mt < 4; ++mt)
      #pragma unroll
      for (int nt = 0; nt < 2; ++nt) {
        acc2[mt][nt][0] = 0.f; acc2[mt][nt][1] = 0.f;
        acc2[mt][nt][2] = 0.f; acc2[mt][nt][3] = 0.f;
      }
    #pragma unroll
    for (int ks = 0; ks < 2; ++ks) {
      const int ka = ks * 32 + kg * 8;
      bf16x8 bh[2], bl[2];
      #pragma unroll
      for (int nt = 0; nt < 2; ++nt) {
        bh[nt] = *(const bf16x8*)&h1h[wv][(nt * 16 + ln) * W2S + ka];
        bl[nt] = *(const bf16x8*)&h1l[wv][(nt * 16 + ln) * W2S + ka];
      }
      #pragma unroll
      for (int mt = 0; mt < 4; ++mt) {
        const bf16x8 a_h = *(const bf16x8*)&W2hS[(mt * 16 + ln) * W2S + ka];
        const bf16x8 a_l = *(const bf16x8*)&W2lS[(mt * 16 + ln) * W2S + ka];
        #pragma unroll
        for (int nt = 0; nt < 2; ++nt) {
          acc2[mt][nt] = __builtin_amdgcn_mfma_f32_16x16x32_bf16(a_h, bh[nt], acc2[mt][nt], 0, 0, 0);
          acc2[mt][nt] = __builtin_amdgcn_mfma_f32_16x16x32_bf16(a_h, bl[nt], acc2[mt][nt], 0, 0, 0);
          acc2[mt][nt] = __builtin_amdgcn_mfma_f32_16x16x32_bf16(a_l, bh[nt], acc2[mt][nt], 0, 0, 0);
        }
      }
    }

    #pragma unroll
    for (int mt = 0; mt < 4; ++mt)
      #pragma unroll
      for (int r = 0; r < 4; ++r) {
        float mx = fmaxf(acc2[mt][0][r], acc2[mt][1][r]);
        mx = fmaxf(mx, __shfl_xor(mx, 1));
        mx = fmaxf(mx, __shfl_xor(mx, 2));
        mx = fmaxf(mx, __shfl_xor(mx, 4));
        mx = fmaxf(mx, __shfl_xor(mx, 8));
        if (ln == mt * 4 + r) {
          const int outcol = mt * 16 + kg * 4 + r;
          m[(size_t)d * 64 + outcol] = fmaxf(mx + bb2[outcol], 0.f);
        }
      }
  }
}

// ==== fused post: y = relu(x + relu(relu(m@W1+b1)@W2+b2) @ Wo + bo), 32 rows/blk ====
__global__ __launch_bounds__(256) void post_fused_kernel(
    const float* __restrict__ m, const float* __restrict__ x,
    const float* __restrict__ W1, const float* __restrict__ b1,
    const float* __restrict__ W2, const float* __restrict__ b2,
    const float* __restrict__ Wo, const float* __restrict__ bo,
    float* __restrict__ y)
{
  __shared__ float Wl[64 * 64];
  __shared__ float Wlo[64 * 128];
  __shared__ float mt[32 * 64];
  __shared__ float ht[32 * 64];
  const int t = threadIdx.x;
  const int c = t & 63, g = t >> 6;
  const long long r0 = (long long)blockIdx.x * 32;
  #pragma unroll
  for (int j = 0; j < 4; ++j) {
    const int off = t * 4 + j * 1024;
    *(float4*)&Wl[off] = *(const float4*)&W1[off];
  }
  #pragma unroll
  for (int j = 0; j < 8; ++j) {
    const int off = t * 4 + j * 1024;
    *(float4*)&Wlo[off] = *(const float4*)&Wo[off];
  }
  #pragma unroll
  for (int j = 0; j < 2; ++j) {
    const int off = t * 4 + j * 1024;
    *(float4*)&mt[off] = *(const float4*)&m[r0 * 64 + off];
  }
  __syncthreads();
  float acc[8];
  {
    const float bv = b1[c];
    #pragma unroll
    for (int i = 0; i < 8; ++i) acc[i] = bv;
  }
  #pragma unroll 4
  for (int k = 0; k < 64; k += 4) {
    const float w0 = Wl[(k + 0) * 64 + c], w1 = Wl[(k + 1) * 64 + c];
    const float w2 = Wl[(k + 2) * 64 + c], w3 = Wl[(k + 3) * 64 + c];
    #pragma unroll
    for (int i = 0; i < 8; ++i) {
      const float4 a = *(const float4*)&mt[(g * 8 + i) * 64 + k];
      acc[i] = fmaf(a.x, w0, fmaf(a.y, w1, fmaf(a.z, w2, fmaf(a.w, w3, acc[i]))));
    }
  }
  #pragma unroll
  for (int i = 0; i < 8; ++i) ht[(g * 8 + i) * 64 + c] = fmaxf(acc[i], 0.f);
  __syncthreads();
  #pragma unroll
  for (int j = 0; j < 4; ++j) {
    const int off = t * 4 + j * 1024;
    *(float4*)&Wl[off] = *(const float4*)&W2[off];
  }
  __syncthreads();
  float acc2[8];
  {
    const float bv = b2[c];
    #pragma unroll
    for (int i = 0; i < 8; ++i) acc2[i] = bv;
  }
  #pragma unroll 4
  for (int k = 0; k < 64; k += 4) {
    const float w0 = Wl[(k + 0) * 64 + c], w1 = Wl[(k + 1) * 64 + c];
    const float w2 = Wl[(k + 2) * 64 + c], w3 = Wl[(k + 3) * 64 + c];
    #pragma unroll
    for (int i = 0; i < 8; ++i) {
      const float4 a = *(const float4*)&ht[(g * 8 + i) * 64 + k];
      acc2[i] = fmaf(a.x, w0, fmaf(a.y, w1, fmaf(a.z, w2, fmaf(a.w, w3, acc2[i]))));
    }
  }
  #pragma unroll
  for (int i = 0; i < 8; ++i) mt[(g * 8 + i) * 64 + c] = fmaxf(acc2[i], 0.f);
  __syncthreads();
  const int c2 = t & 127, g2 = t >> 7;
  float acco[16];
  {
    const float bv = bo[c2];
    #pragma unroll
    for (int i = 0; i < 16; ++i) acco[i] = bv;
  }
  #pragma unroll 4
  for (int k = 0; k < 64; k += 4) {
    const float w0 = Wlo[(k + 0) * 128 + c2], w1 = Wlo[(k + 1) * 128 + c2];
    const float w2 = Wlo[(k + 2) * 128 + c2], w3 = Wlo[(k + 3) * 128 + c2];
    #pragma unroll
    for (int i = 0; i < 16; ++i) {
      const float4 a = *(const float4*)&mt[(g2 * 16 + i) * 64 + k];
      acco[i] = fmaf(a.x, w0, fmaf(a.y, w1, fmaf(a.z, w2, fmaf(a.w, w3, acco[i]))));
    }
  }
  #pragma unroll
  for (int i = 0; i < 16; ++i) {
    const long long idx = (r0 + g2 * 16 + i) * 128 + c2;
    y[idx] = fmaxf(x[idx] + acco[i], 0.f);
  }
}

// ============ score layer: y = relu(x @ W + b), (N,128)@(128,128) ============
__global__ __launch_bounds__(256) void score_layer_kernel(
    const float* __restrict__ x, const float* __restrict__ W,
    const float* __restrict__ bias, float* __restrict__ y)
{
  __shared__ float Wl[64 * 128];
  __shared__ float xt[16 * 128];
  const int t = threadIdx.x;
  const int c = t & 127, g = t >> 7;
  const long long r0 = (long long)blockIdx.x * 16;
  #pragma unroll
  for (int j = 0; j < 2; ++j) {
    const int off = t * 4 + j * 1024;
    *(float4*)&xt[off] = *(const float4*)&x[r0 * 128 + off];
  }
  float acc[8];
  {
    const float bv = bias[c];
    #pragma unroll
    for (int i = 0; i < 8; ++i) acc[i] = bv;
  }
  #pragma unroll 1
  for (int kc = 0; kc < 128; kc += 64) {
    __syncthreads();
    #pragma unroll
    for (int j = 0; j < 8; ++j) {
      const int off = t * 4 + j * 1024;
      *(float4*)&Wl[off] = *(const float4*)&W[(long long)kc * 128 + off];
    }
    __syncthreads();
    #pragma unroll 4
    for (int k = 0; k < 64; k += 4) {
      const float w0 = Wl[(k + 0) * 128 + c], w1 = Wl[(k + 1) * 128 + c];
      const float w2 = Wl[(k + 2) * 128 + c], w3 = Wl[(k + 3) * 128 + c];
      #pragma unroll
      for (int i = 0; i < 8; ++i) {
        const float4 a = *(const float4*)&xt[(g * 8 + i) * 128 + kc + k];
        acc[i] = fmaf(a.x, w0, fmaf(a.y, w1, fmaf(a.z, w2, fmaf(a.w, w3, acc[i]))));
      }
    }
  }
  #pragma unroll
  for (int i = 0; i < 8; ++i)
    y[(r0 + g * 8 + i) * 128 + c] = fmaxf(acc[i], 0.f);
}

// ============ scores = x @ pred_W + pred_b ============
__global__ __launch_bounds__(256) void dot_kernel(
    const float* __restrict__ x, const float* __restrict__ pW,
    const float* __restrict__ pb, float* __restrict__ out)
{
  const int t = threadIdx.x;
  const int l = t & 63;
  const long long r = (long long)blockIdx.x * 4 + (t >> 6);
  const float* xr = x + r * 128;
  float acc = fmaf(xr[l], pW[l], xr[l + 64] * pW[l + 64]);
  for (int o = 32; o; o >>= 1) acc += __shfl_xor(acc, o);
  if (l == 0) out[r] = acc + pb[0];
}

extern "C" void kernel_launch(void* const* d_in, const int* in_sizes, int n_in,
                              void* d_out, int out_size, void* d_ws, size_t ws_size,
                              hipStream_t stream)
{
  const float* detF    = (const float*)d_in[0];
  const float* pairRaw = (const float*)d_in[1];
  const int*   cIdx    = (const int*)d_in[2];
  const int*   nIdx    = (const int*)d_in[3];
  const float* gW1 = (const float*)d_in[4];   const float* gb1 = (const float*)d_in[5];
  const float* gW2 = (const float*)d_in[6];   const float* gb2 = (const float*)d_in[7];
  const float* gW3 = (const float*)d_in[8];   const float* gb3 = (const float*)d_in[9];
  const float* fc1W = (const float*)d_in[10]; const float* fc1b = (const float*)d_in[11];
  const float* pwW1 = (const float*)d_in[12]; const float* pwb1 = (const float*)d_in[13];
  const float* pwW2 = (const float*)d_in[14]; const float* pwb2 = (const float*)d_in[15];
  const float* poW1 = (const float*)d_in[16]; const float* pob1 = (const float*)d_in[17];
  const float* poW2 = (const float*)d_in[18]; const float* pob2 = (const float*)d_in[19];
  const float* outW = (const float*)d_in[20]; const float* outb = (const float*)d_in[21];
  const float* sW = (const float*)d_in[22];   const float* sb = (const float*)d_in[23];
  const float* predW = (const float*)d_in[24]; const float* predb = (const float*)d_in[25];
  float* out = (float*)d_out;
  (void)cIdx;   // cIdxs == repeat(arange(N), DEG) per setup; d = e >> 5

  ushort* w2h  = (ushort*)d_ws;
  ushort* w2l  = w2h + 65536;
  ushort* w3h  = w2l + 65536;
  ushort* w3l  = w3h + 8192;
  ushort* w1eh = w3l + 8192;
  ushort* w1el = w1eh + 24576;
  ushort* w2eh = w1el + 24576;
  ushort* w2el = w2eh + 16384;
  ushort* pair_h = w2el + 16384;
  ushort* pair_l = pair_h + (size_t)E_EDGES * 32;
  ushort* f_h    = pair_l + (size_t)E_EDGES * 32;
  ushort* f_l    = f_h + (size_t)N_DETS * 32;
  float* f  = (float*)(f_l + (size_t)N_DETS * 32);
  float* m  = f  + (size_t)N_DETS * 32;
  float* mm = m  + (size_t)N_DETS * 64;
  float* xa = mm + (size_t)N_DETS * 64;
  float* xb = xa + (size_t)N_DETS * 128;

  hipMemcpyAsync(xa, detF, (size_t)N_DETS * 128 * sizeof(float),
                 hipMemcpyDeviceToDevice, stream);

  split_w_kernel<<<256, 256, 0, stream>>>(gW2, w2h, w2l, 256);
  split_w_kernel<<<32, 256, 0, stream>>>(gW3, w3h, w3l, 32);
  split_edge_w_kernel<<<4, 256, 0, stream>>>(pwW1, pwW2, w1eh, w1el, w2eh, w2el);

  pair_mlp_kernel<<<256, 1024, 0, stream>>>(pairRaw, gW1, gb1,
      w2h, w2l, gb2, w3h, w3l, gb3, pair_h, pair_l);

  float* xin = xa;
  float* xout = xb;
  for (int b = 0; b < 4; ++b) {
    fc1_kernel<<<N_DETS / 8, 256, 0, stream>>>(xin, fc1W + b * 4096, fc1b + b * 32,
        f, f_h, f_l);
    edge_kernel<<<EDGE_GRID, 512, 0, stream>>>(pair_h, pair_l, f, f_h, f_l, nIdx,
        pwW1 + b * 6144, pwb1 + b * 64,
        w1eh + b * 6144, w1el + b * 6144, w2eh + b * 4096, w2el + b * 4096,
        pwb2 + b * 64, m);
    post_fused_kernel<<<N_DETS / 32, 256, 0, stream>>>(m, xin,
        poW1 + b * 4096, pob1 + b * 64, poW2 + b * 4096, pob2 + b * 64,
        outW + b * 8192, outb + b * 128, xout);
    float* tmp = xout; xout = xin; xin = tmp;
  }
  for (int i = 0; i < 3; ++i) {
    score_layer_kernel<<<N_DETS / 16, 256, 0, stream>>>(xin, sW + i * 16384, sb + i * 128, xout);
    float* tmp = xout; xout = xin; xin = tmp;
  }
  dot_kernel<<<N_DETS / 4, 256, 0, stream>>>(xin, predW, predb, out);
}

// Round 15
// 850.368 us; speedup vs baseline: 1.2391x; 1.2391x over previous
//
#include <hip/hip_runtime.h>

// R15: revert R14 swizzle (wrong premise: b128 reads already at 8-phase floor;
// counter is an artifact; and non-affine addressing spilled -> 678MB scratch).
// Back to R13 affine stride-264 + barrier cut 5->3: h2 to separate LDS buffer
// (no L2read/epi-write hazard barrier), w3 B-frags from L2-hot global, next
// rawt prefetched during L3 phase. Numerics identical to R13.
#define N_DETS 16384
#define DEG 32
#define E_EDGES (N_DETS * DEG)   // 524288
#define EDGE_GRID 512

typedef __attribute__((ext_vector_type(8))) short bf16x8;
typedef __attribute__((ext_vector_type(4))) float f32x4;

__device__ __forceinline__ ushort f32_to_bf16(float v) {
  unsigned u = __float_as_uint(v);
  u += 0x7FFFu + ((u >> 16) & 1u);    // round-to-nearest-even
  return (ushort)(u >> 16);
}
__device__ __forceinline__ float bf16_to_f32(ushort h) {
  return __uint_as_float((unsigned)h << 16);
}

// ============ prep: out[n][k] = split_hi/lo(W[k][n]); K==256, grid=N ============
__global__ __launch_bounds__(256) void split_w_kernel(
    const float* __restrict__ W, ushort* __restrict__ hi, ushort* __restrict__ lo, int N)
{
  const int n = blockIdx.x, k = threadIdx.x;
  const float v = W[(size_t)k * N + n];
  const ushort h = f32_to_bf16(v);
  const ushort l = f32_to_bf16(v - bf16_to_f32(h));
  hi[(size_t)n * 256 + k] = h;
  lo[(size_t)n * 256 + k] = l;
}

// ============ prep: edge-block W1 (96x64) + W2 (64x64) -> [col][k] split ============
__global__ __launch_bounds__(256) void split_edge_w_kernel(
    const float* __restrict__ W1all, const float* __restrict__ W2all,
    ushort* __restrict__ w1h, ushort* __restrict__ w1l,
    ushort* __restrict__ w2h, ushort* __restrict__ w2l)
{
  const int b = blockIdx.x;
  const float* W1 = W1all + b * 6144;
  const float* W2 = W2all + b * 4096;
  for (int i = threadIdx.x; i < 6144; i += 256) {
    const int col = i / 96, k = i % 96;
    const float v = W1[k * 64 + col];
    const ushort h = f32_to_bf16(v);
    w1h[b * 6144 + col * 96 + k] = h;
    w1l[b * 6144 + col * 96 + k] = f32_to_bf16(v - bf16_to_f32(h));
  }
  for (int i = threadIdx.x; i < 4096; i += 256) {
    const int col = i >> 6, k = i & 63;
    const float v = W2[k * 64 + col];
    const ushort h = f32_to_bf16(v);
    w2h[b * 4096 + col * 64 + k] = h;
    w2l[b * 4096 + col * 64 + k] = f32_to_bf16(v - bf16_to_f32(h));
  }
}

// ===================== pairwise MLP: 9 -> 256 -> 256 -> 32 =====================
#define A_STRIDE 264

__global__ __launch_bounds__(1024, 4) void pair_mlp_kernel(
    const float* __restrict__ raw,
    const float* __restrict__ W1, const float* __restrict__ b1,
    const ushort* __restrict__ w2h, const ushort* __restrict__ w2l,
    const float* __restrict__ b2,
    const ushort* __restrict__ w3h, const ushort* __restrict__ w3l,
    const float* __restrict__ b3,
    ushort* __restrict__ pair_h, ushort* __restrict__ pair_l)
{
  __shared__ __align__(16) ushort ah[64 * A_STRIDE];    // 33.8 KB (h1)
  __shared__ __align__(16) ushort al[64 * A_STRIDE];    // 33.8 KB
  __shared__ __align__(16) ushort h2h[64 * A_STRIDE];   // 33.8 KB (h2)
  __shared__ __align__(16) ushort h2l[64 * A_STRIDE];   // 33.8 KB
  __shared__ __align__(16) float rawt[64 * 12];         // 3 KB  => 138.2 KB

  const int t = threadIdx.x;
  const int lane = t & 63, wv = t >> 6;    // 16 waves
  const int ln = lane & 15, kg = lane >> 4;

  // one-time: W2 split fragments -> registers (wave wv owns cols 16wv..16wv+15)
  bf16x8 b2hreg[8], b2lreg[8];
  #pragma unroll
  for (int ks = 0; ks < 8; ++ks) {
    const size_t bo = (size_t)(wv * 16 + ln) * 256 + ks * 32 + kg * 8;
    b2hreg[ks] = *(const bf16x8*)&w2h[bo];
    b2lreg[ks] = *(const bf16x8*)&w2l[bo];
  }
  const float bias2 = b2[wv * 16 + ln];
  const int mt3 = (wv >> 1) & 3, nt3 = wv & 1;
  const float b3v = b3[nt3 * 16 + ln];
  const ushort* w3hp = w3h + (size_t)(nt3 * 16 + ln) * 256;   // L2-hot 16 KB table
  const ushort* w3lp = w3l + (size_t)(nt3 * 16 + ln) * 256;

  // prologue: stage rawt for first group
  int grp = blockIdx.x;
  if (t < 64 * 9) rawt[(t / 9) * 12 + (t % 9)] = raw[(long long)grp * 576 + t];
  __syncthreads();   // sync1

  for (; grp < E_EDGES / 64; grp += gridDim.x) {
    const long long e0 = (long long)grp * 64;

    // ---- phase B / layer 1: thread owns col (t&255), rows (t>>8)*16..+16 ----
    {
      const int col = t & 255, r0 = (t >> 8) * 16;
      const float bv = b1[col];
      float wk[9];
      #pragma unroll
      for (int k = 0; k < 9; ++k) wk[k] = W1[k * 256 + col];
      #pragma unroll
      for (int r = 0; r < 16; ++r) {
        const int row = r0 + r;
        const float4 ra = *(const float4*)&rawt[row * 12];
        const float4 rb = *(const float4*)&rawt[row * 12 + 4];
        const float rc = rawt[row * 12 + 8];
        float s = bv;
        s = fmaf(ra.x, wk[0], s); s = fmaf(ra.y, wk[1], s);
        s = fmaf(ra.z, wk[2], s); s = fmaf(ra.w, wk[3], s);
        s = fmaf(rb.x, wk[4], s); s = fmaf(rb.y, wk[5], s);
        s = fmaf(rb.z, wk[6], s); s = fmaf(rb.w, wk[7], s);
        s = fmaf(rc, wk[8], s);
        const float v = fmaxf(s, 0.f);
        const ushort h = f32_to_bf16(v);
        ah[row * A_STRIDE + col] = h;
        al[row * A_STRIDE + col] = f32_to_bf16(v - bf16_to_f32(h));
      }
    }
    __syncthreads();   // sync2: h1 ready

    // ---- phase C / layer 2 K-loop + epilogue -> h2 buffers (no hazard) ----
    f32x4 acc[4];
    #pragma unroll
    for (int mt = 0; mt < 4; ++mt) {
      acc[mt][0] = 0.f; acc[mt][1] = 0.f; acc[mt][2] = 0.f; acc[mt][3] = 0.f;
    }
    #pragma unroll
    for (int ks = 0; ks < 8; ++ks) {
      const int ka = ks * 32 + kg * 8;
      #pragma unroll
      for (int mt = 0; mt < 4; ++mt) {
        const bf16x8 ahf = *(const bf16x8*)&ah[(mt * 16 + ln) * A_STRIDE + ka];
        const bf16x8 alf = *(const bf16x8*)&al[(mt * 16 + ln) * A_STRIDE + ka];
        acc[mt] = __builtin_amdgcn_mfma_f32_16x16x32_bf16(ahf, b2hreg[ks], acc[mt], 0, 0, 0);
        acc[mt] = __builtin_amdgcn_mfma_f32_16x16x32_bf16(alf, b2hreg[ks], acc[mt], 0, 0, 0);
        acc[mt] = __builtin_amdgcn_mfma_f32_16x16x32_bf16(ahf, b2lreg[ks], acc[mt], 0, 0, 0);
      }
    }
    {
      const int colg = wv * 16 + ln;
      #pragma unroll
      for (int mt = 0; mt < 4; ++mt)
        #pragma unroll
        for (int r = 0; r < 4; ++r) {
          const int rowe = mt * 16 + kg * 4 + r;
          const float v = fmaxf(acc[mt][r] + bias2, 0.f);
          const ushort h = f32_to_bf16(v);
          h2h[rowe * A_STRIDE + colg] = h;
          h2l[rowe * A_STRIDE + colg] = f32_to_bf16(v - bf16_to_f32(h));
        }
    }
    __syncthreads();   // sync3: L2 reads of h1 done + h2 ready

    // ---- phase D: prefetch next rawt; layer 3 (waves 0-7) from h2 + global w3 ----
    {
      const int grpn = grp + (int)gridDim.x;
      if (t < 64 * 9 && grpn < E_EDGES / 64)
        rawt[(t / 9) * 12 + (t % 9)] = raw[(long long)grpn * 576 + t];
    }
    if (wv < 8) {
      f32x4 acc3;
      acc3[0] = 0.f; acc3[1] = 0.f; acc3[2] = 0.f; acc3[3] = 0.f;
      #pragma unroll
      for (int ks = 0; ks < 8; ++ks) {
        const int ka = ks * 32 + kg * 8;
        const bf16x8 a_h = *(const bf16x8*)&h2h[(mt3 * 16 + ln) * A_STRIDE + ka];
        const bf16x8 a_l = *(const bf16x8*)&h2l[(mt3 * 16 + ln) * A_STRIDE + ka];
        const bf16x8 b_h = *(const bf16x8*)&w3hp[ka];
        const bf16x8 b_l = *(const bf16x8*)&w3lp[ka];
        acc3 = __builtin_amdgcn_mfma_f32_16x16x32_bf16(a_h, b_h, acc3, 0, 0, 0);
        acc3 = __builtin_amdgcn_mfma_f32_16x16x32_bf16(a_l, b_h, acc3, 0, 0, 0);
        acc3 = __builtin_amdgcn_mfma_f32_16x16x32_bf16(a_h, b_l, acc3, 0, 0, 0);
      }
      const int col3 = nt3 * 16 + ln;
      #pragma unroll
      for (int r = 0; r < 4; ++r) {
        const int rowe = mt3 * 16 + kg * 4 + r;
        const float v = fmaxf(acc3[r] + b3v, 0.f);
        const ushort h = f32_to_bf16(v);
        const size_t idx = (size_t)(e0 + rowe) * 32 + col3;
        pair_h[idx] = h;
        pair_l[idx] = f32_to_bf16(v - bf16_to_f32(h));
      }
    }
    __syncthreads();   // sync1 for next iter (rawt ready; h1 free to overwrite)
  }
}

// ========== f = relu(x @ fc1_W + b) : (N,128)@(128,32); emits f32 + split ==========
__global__ __launch_bounds__(256) void fc1_kernel(
    const float* __restrict__ x, const float* __restrict__ W,
    const float* __restrict__ b, float* __restrict__ f,
    ushort* __restrict__ f_h, ushort* __restrict__ f_l)
{
  __shared__ float Wl[128 * 32];
  const int t = threadIdx.x;
  #pragma unroll
  for (int j = 0; j < 4; ++j) {
    const int off = t * 4 + j * 1024;
    *(float4*)&Wl[off] = *(const float4*)&W[off];
  }
  __syncthreads();
  const int c = t & 31, rr = t >> 5;
  const long long r = (long long)blockIdx.x * 8 + rr;
  const float* xr = x + r * 128;
  float acc = b[c];
  #pragma unroll 8
  for (int k = 0; k < 128; k += 4) {
    const float4 a = *(const float4*)&xr[k];
    acc = fmaf(a.x, Wl[(k + 0) * 32 + c], acc);
    acc = fmaf(a.y, Wl[(k + 1) * 32 + c], acc);
    acc = fmaf(a.z, Wl[(k + 2) * 32 + c], acc);
    acc = fmaf(a.w, Wl[(k + 3) * 32 + c], acc);
  }
  const float v = fmaxf(acc, 0.f);
  f[r * 32 + c] = v;
  const ushort h = f32_to_bf16(v);
  f_h[r * 32 + c] = h;
  f_l[r * 32 + c] = f32_to_bf16(v - bf16_to_f32(h));
}

// ====== edge MLP (96->64->64) + segment-max, split-bf16 MFMA, persistent ======
#define W1S 104
#define W2S 72
#define CTS 36

__global__ __launch_bounds__(512, 2) void edge_kernel(
    const ushort* __restrict__ pair_h, const ushort* __restrict__ pair_l,
    const float* __restrict__ f,
    const ushort* __restrict__ f_h, const ushort* __restrict__ f_l,
    const int* __restrict__ nIdxs,
    const float* __restrict__ W1g, const float* __restrict__ bb1,
    const ushort* __restrict__ gw1h, const ushort* __restrict__ gw1l,
    const ushort* __restrict__ gw2h, const ushort* __restrict__ gw2l,
    const float* __restrict__ bb2,
    float* __restrict__ m)
{
  __shared__ __align__(16) ushort W1hS[64 * W1S], W1lS[64 * W1S];
  __shared__ __align__(16) ushort W2hS[64 * W2S], W2lS[64 * W2S];
  __shared__ __align__(16) float  W1cT[64 * CTS];
  __shared__ __align__(16) ushort h1h[8][32 * W2S], h1l[8][32 * W2S];

  const int t = threadIdx.x;
  const int lane = t & 63, wv = t >> 6;
  const int ln = lane & 15, kg = lane >> 4;

  for (int i = t; i < 1536; i += 512) {
    const int idx = i * 4, row = idx / 96, k = idx % 96;
    *(ushort4*)&W1hS[row * W1S + k] = *(const ushort4*)&gw1h[idx];
    *(ushort4*)&W1lS[row * W1S + k] = *(const ushort4*)&gw1l[idx];
  }
  for (int i = t; i < 1024; i += 512) {
    const int idx = i * 4, row = idx >> 6, k = idx & 63;
    *(ushort4*)&W2hS[row * W2S + k] = *(const ushort4*)&gw2h[idx];
    *(ushort4*)&W2lS[row * W2S + k] = *(const ushort4*)&gw2l[idx];
  }
  for (int i = t; i < 2048; i += 512) {
    const int col = i >> 5, j = i & 31;
    W1cT[col * CTS + j] = W1g[(32 + j) * 64 + col];
  }
  __syncthreads();

  for (int dg = blockIdx.x; dg < N_DETS / 8; dg += gridDim.x) {
    const int d = dg * 8 + wv;
    const long long e0 = (long long)d * 32;

    float cfs[4];
    {
      const float4 fv0 = *(const float4*)&f[(size_t)d * 32 + kg * 8];
      const float4 fv1 = *(const float4*)&f[(size_t)d * 32 + kg * 8 + 4];
      #pragma unroll
      for (int nt = 0; nt < 4; ++nt) {
        const int col = nt * 16 + ln;
        const float4 w0 = *(const float4*)&W1cT[col * CTS + kg * 8];
        const float4 w1 = *(const float4*)&W1cT[col * CTS + kg * 8 + 4];
        float s = fv0.x * w0.x + fv0.y * w0.y + fv0.z * w0.z + fv0.w * w0.w
                + fv1.x * w1.x + fv1.y * w1.y + fv1.z * w1.z + fv1.w * w1.w;
        s += __shfl_xor(s, 16);
        s += __shfl_xor(s, 32);
        cfs[nt] = s + bb1[col];
      }
    }

    f32x4 acc1[4][2];
    #pragma unroll
    for (int nt = 0; nt < 4; ++nt)
      #pragma unroll
      for (int mt = 0; mt < 2; ++mt) {
        acc1[nt][mt][0] = 0.f; acc1[nt][mt][1] = 0.f;
        acc1[nt][mt][2] = 0.f; acc1[nt][mt][3] = 0.f;
      }
    bf16x8 ph[2], pl_[2], nh[2], nl_[2];
    #pragma unroll
    for (int mt = 0; mt < 2; ++mt) {
      const long long row = e0 + mt * 16 + ln;
      ph[mt]  = *(const bf16x8*)&pair_h[row * 32 + kg * 8];
      pl_[mt] = *(const bf16x8*)&pair_l[row * 32 + kg * 8];
      const int n = nIdxs[row];
      bf16x8 vh = *(const bf16x8*)&f_h[(size_t)n * 32 + kg * 8];
      bf16x8 vl = *(const bf16x8*)&f_l[(size_t)n * 32 + kg * 8];
      if (n == d) { vh = (bf16x8){0,0,0,0,0,0,0,0}; vl = (bf16x8){0,0,0,0,0,0,0,0}; }
      nh[mt] = vh; nl_[mt] = vl;
    }
    #pragma unroll
    for (int nt = 0; nt < 4; ++nt) {
      const int bro = (nt * 16 + ln) * W1S;
      const bf16x8 b0h = *(const bf16x8*)&W1hS[bro + kg * 8];
      const bf16x8 b0l = *(const bf16x8*)&W1lS[bro + kg * 8];
      const bf16x8 b1h = *(const bf16x8*)&W1hS[bro + 64 + kg * 8];
      const bf16x8 b1l = *(const bf16x8*)&W1lS[bro + 64 + kg * 8];
      #pragma unroll
      for (int mt = 0; mt < 2; ++mt) {
        acc1[nt][mt] = __builtin_amdgcn_mfma_f32_16x16x32_bf16(ph[mt], b0h, acc1[nt][mt], 0, 0, 0);
        acc1[nt][mt] = __builtin_amdgcn_mfma_f32_16x16x32_bf16(pl_[mt], b0h, acc1[nt][mt], 0, 0, 0);
        acc1[nt][mt] = __builtin_amdgcn_mfma_f32_16x16x32_bf16(ph[mt], b0l, acc1[nt][mt], 0, 0, 0);
        acc1[nt][mt] = __builtin_amdgcn_mfma_f32_16x16x32_bf16(nh[mt], b1h, acc1[nt][mt], 0, 0, 0);
        acc1[nt][mt] = __builtin_amdgcn_mfma_f32_16x16x32_bf16(nl_[mt], b1h, acc1[nt][mt], 0, 0, 0);
        acc1[nt][mt] = __builtin_amdgcn_mfma_f32_16x16x32_bf16(nh[mt], b1l, acc1[nt][mt], 0, 0, 0);
      }
    }

    #pragma unroll
    for (int nt = 0; nt < 4; ++nt) {
      const int col = nt * 16 + ln;
      #pragma unroll
      for (int mt = 0; mt < 2; ++mt)
        #pragma unroll
        for (int r = 0; r < 4; ++r) {
          const int row = mt * 16 + kg * 4 + r;
          const float v = fmaxf(acc1[nt][mt][r] + cfs[nt], 0.f);
          const ushort h = f32_to_bf16(v);
          h1h[wv][row * W2S + col] = h;
          h1l[wv][row * W2S + col] = f32_to_bf16(v - bf16_to_f32(h));
        }
    }

    f32x4 acc2[4][2];
    #pragma unroll
    for (int mt = 0; mt < 4; ++mt)
      #pragma unroll
      for (int nt = 0; nt < 2; ++nt) {
        acc2[mt][nt][0] = 0.f; acc2[mt][nt][1] = 0.f;
        acc2[mt][nt][2] = 0.f; acc2[mt][nt][3] = 0.f;
      }
    #pragma unroll
    for (int ks = 0; ks < 2; ++ks) {
      const int ka = ks * 32 + kg * 8;
      bf16x8 bh[2], bl[2];
      #pragma unroll
      for (int nt = 0; nt < 2; ++nt) {
        bh[nt] = *(const bf16x8*)&h1h[wv][(nt * 16 + ln) * W2S + ka];
        bl[nt] = *(const bf16x8*)&h1l[wv][(nt * 16 + ln) * W2S + ka];
      }
      #pragma unroll
      for (int mt = 0; mt < 4; ++mt) {
        const bf16x8 a_h = *(const bf16x8*)&W2hS[(mt * 16 + ln) * W2S + ka];
        const bf16x8 a_l = *(const bf16x8*)&W2lS[(mt * 16 + ln) * W2S + ka];
        #pragma unroll
        for (int nt = 0; nt < 2; ++nt) {
          acc2[mt][nt] = __builtin_amdgcn_mfma_f32_16x16x32_bf16(a_h, bh[nt], acc2[mt][nt], 0, 0, 0);
          acc2[mt][nt] = __builtin_amdgcn_mfma_f32_16x16x32_bf16(a_h, bl[nt], acc2[mt][nt], 0, 0, 0);
          acc2[mt][nt] = __builtin_amdgcn_mfma_f32_16x16x32_bf16(a_l, bh[nt], acc2[mt][nt], 0, 0, 0);
        }
      }
    }

    #pragma unroll
    for (int mt = 0; mt < 4; ++mt)
      #pragma unroll
      for (int r = 0; r < 4; ++r) {
        float mx = fmaxf(acc2[mt][0][r], acc2[mt][1][r]);
        mx = fmaxf(mx, __shfl_xor(mx, 1));
        mx = fmaxf(mx, __shfl_xor(mx, 2));
        mx = fmaxf(mx, __shfl_xor(mx, 4));
        mx = fmaxf(mx, __shfl_xor(mx, 8));
        if (ln == mt * 4 + r) {
          const int outcol = mt * 16 + kg * 4 + r;
          m[(size_t)d * 64 + outcol] = fmaxf(mx + bb2[outcol], 0.f);
        }
      }
  }
}

// ==== fused post: y = relu(x + relu(relu(m@W1+b1)@W2+b2) @ Wo + bo), 32 rows/blk ====
__global__ __launch_bounds__(256) void post_fused_kernel(
    const float* __restrict__ m, const float* __restrict__ x,
    const float* __restrict__ W1, const float* __restrict__ b1,
    const float* __restrict__ W2, const float* __restrict__ b2,
    const float* __restrict__ Wo, const float* __restrict__ bo,
    float* __restrict__ y)
{
  __shared__ float Wl[64 * 64];
  __shared__ float Wlo[64 * 128];
  __shared__ float mt[32 * 64];
  __shared__ float ht[32 * 64];
  const int t = threadIdx.x;
  const int c = t & 63, g = t >> 6;
  const long long r0 = (long long)blockIdx.x * 32;
  #pragma unroll
  for (int j = 0; j < 4; ++j) {
    const int off = t * 4 + j * 1024;
    *(float4*)&Wl[off] = *(const float4*)&W1[off];
  }
  #pragma unroll
  for (int j = 0; j < 8; ++j) {
    const int off = t * 4 + j * 1024;
    *(float4*)&Wlo[off] = *(const float4*)&Wo[off];
  }
  #pragma unroll
  for (int j = 0; j < 2; ++j) {
    const int off = t * 4 + j * 1024;
    *(float4*)&mt[off] = *(const float4*)&m[r0 * 64 + off];
  }
  __syncthreads();
  float acc[8];
  {
    const float bv = b1[c];
    #pragma unroll
    for (int i = 0; i < 8; ++i) acc[i] = bv;
  }
  #pragma unroll 4
  for (int k = 0; k < 64; k += 4) {
    const float w0 = Wl[(k + 0) * 64 + c], w1 = Wl[(k + 1) * 64 + c];
    const float w2 = Wl[(k + 2) * 64 + c], w3 = Wl[(k + 3) * 64 + c];
    #pragma unroll
    for (int i = 0; i < 8; ++i) {
      const float4 a = *(const float4*)&mt[(g * 8 + i) * 64 + k];
      acc[i] = fmaf(a.x, w0, fmaf(a.y, w1, fmaf(a.z, w2, fmaf(a.w, w3, acc[i]))));
    }
  }
  #pragma unroll
  for (int i = 0; i < 8; ++i) ht[(g * 8 + i) * 64 + c] = fmaxf(acc[i], 0.f);
  __syncthreads();
  #pragma unroll
  for (int j = 0; j < 4; ++j) {
    const int off = t * 4 + j * 1024;
    *(float4*)&Wl[off] = *(const float4*)&W2[off];
  }
  __syncthreads();
  float acc2[8];
  {
    const float bv = b2[c];
    #pragma unroll
    for (int i = 0; i < 8; ++i) acc2[i] = bv;
  }
  #pragma unroll 4
  for (int k = 0; k < 64; k += 4) {
    const float w0 = Wl[(k + 0) * 64 + c], w1 = Wl[(k + 1) * 64 + c];
    const float w2 = Wl[(k + 2) * 64 + c], w3 = Wl[(k + 3) * 64 + c];
    #pragma unroll
    for (int i = 0; i < 8; ++i) {
      const float4 a = *(const float4*)&ht[(g * 8 + i) * 64 + k];
      acc2[i] = fmaf(a.x, w0, fmaf(a.y, w1, fmaf(a.z, w2, fmaf(a.w, w3, acc2[i]))));
    }
  }
  #pragma unroll
  for (int i = 0; i < 8; ++i) mt[(g * 8 + i) * 64 + c] = fmaxf(acc2[i], 0.f);
  __syncthreads();
  const int c2 = t & 127, g2 = t >> 7;
  float acco[16];
  {
    const float bv = bo[c2];
    #pragma unroll
    for (int i = 0; i < 16; ++i) acco[i] = bv;
  }
  #pragma unroll 4
  for (int k = 0; k < 64; k += 4) {
    const float w0 = Wlo[(k + 0) * 128 + c2], w1 = Wlo[(k + 1) * 128 + c2];
    const float w2 = Wlo[(k + 2) * 128 + c2], w3 = Wlo[(k + 3) * 128 + c2];
    #pragma unroll
    for (int i = 0; i < 16; ++i) {
      const float4 a = *(const float4*)&mt[(g2 * 16 + i) * 64 + k];
      acco[i] = fmaf(a.x, w0, fmaf(a.y, w1, fmaf(a.z, w2, fmaf(a.w, w3, acco[i]))));
    }
  }
  #pragma unroll
  for (int i = 0; i < 16; ++i) {
    const long long idx = (r0 + g2 * 16 + i) * 128 + c2;
    y[idx] = fmaxf(x[idx] + acco[i], 0.f);
  }
}

// ============ score layer: y = relu(x @ W + b), (N,128)@(128,128) ============
__global__ __launch_bounds__(256) void score_layer_kernel(
    const float* __restrict__ x, const float* __restrict__ W,
    const float* __restrict__ bias, float* __restrict__ y)
{
  __shared__ float Wl[64 * 128];
  __shared__ float xt[16 * 128];
  const int t = threadIdx.x;
  const int c = t & 127, g = t >> 7;
  const long long r0 = (long long)blockIdx.x * 16;
  #pragma unroll
  for (int j = 0; j < 2; ++j) {
    const int off = t * 4 + j * 1024;
    *(float4*)&xt[off] = *(const float4*)&x[r0 * 128 + off];
  }
  float acc[8];
  {
    const float bv = bias[c];
    #pragma unroll
    for (int i = 0; i < 8; ++i) acc[i] = bv;
  }
  #pragma unroll 1
  for (int kc = 0; kc < 128; kc += 64) {
    __syncthreads();
    #pragma unroll
    for (int j = 0; j < 8; ++j) {
      const int off = t * 4 + j * 1024;
      *(float4*)&Wl[off] = *(const float4*)&W[(long long)kc * 128 + off];
    }
    __syncthreads();
    #pragma unroll 4
    for (int k = 0; k < 64; k += 4) {
      const float w0 = Wl[(k + 0) * 128 + c], w1 = Wl[(k + 1) * 128 + c];
      const float w2 = Wl[(k + 2) * 128 + c], w3 = Wl[(k + 3) * 128 + c];
      #pragma unroll
      for (int i = 0; i < 8; ++i) {
        const float4 a = *(const float4*)&xt[(g * 8 + i) * 128 + kc + k];
        acc[i] = fmaf(a.x, w0, fmaf(a.y, w1, fmaf(a.z, w2, fmaf(a.w, w3, acc[i]))));
      }
    }
  }
  #pragma unroll
  for (int i = 0; i < 8; ++i)
    y[(r0 + g * 8 + i) * 128 + c] = fmaxf(acc[i], 0.f);
}

// ============ scores = x @ pred_W + pred_b ============
__global__ __launch_bounds__(256) void dot_kernel(
    const float* __restrict__ x, const float* __restrict__ pW,
    const float* __restrict__ pb, float* __restrict__ out)
{
  const int t = threadIdx.x;
  const int l = t & 63;
  const long long r = (long long)blockIdx.x * 4 + (t >> 6);
  const float* xr = x + r * 128;
  float acc = fmaf(xr[l], pW[l], xr[l + 64] * pW[l + 64]);
  for (int o = 32; o; o >>= 1) acc += __shfl_xor(acc, o);
  if (l == 0) out[r] = acc + pb[0];
}

extern "C" void kernel_launch(void* const* d_in, const int* in_sizes, int n_in,
                              void* d_out, int out_size, void* d_ws, size_t ws_size,
                              hipStream_t stream)
{
  const float* detF    = (const float*)d_in[0];
  const float* pairRaw = (const float*)d_in[1];
  const int*   cIdx    = (const int*)d_in[2];
  const int*   nIdx    = (const int*)d_in[3];
  const float* gW1 = (const float*)d_in[4];   const float* gb1 = (const float*)d_in[5];
  const float* gW2 = (const float*)d_in[6];   const float* gb2 = (const float*)d_in[7];
  const float* gW3 = (const float*)d_in[8];   const float* gb3 = (const float*)d_in[9];
  const float* fc1W = (const float*)d_in[10]; const float* fc1b = (const float*)d_in[11];
  const float* pwW1 = (const float*)d_in[12]; const float* pwb1 = (const float*)d_in[13];
  const float* pwW2 = (const float*)d_in[14]; const float* pwb2 = (const float*)d_in[15];
  const float* poW1 = (const float*)d_in[16]; const float* pob1 = (const float*)d_in[17];
  const float* poW2 = (const float*)d_in[18]; const float* pob2 = (const float*)d_in[19];
  const float* outW = (const float*)d_in[20]; const float* outb = (const float*)d_in[21];
  const float* sW = (const float*)d_in[22];   const float* sb = (const float*)d_in[23];
  const float* predW = (const float*)d_in[24]; const float* predb = (const float*)d_in[25];
  float* out = (float*)d_out;
  (void)cIdx;   // cIdxs == repeat(arange(N), DEG) per setup; d = e >> 5

  ushort* w2h  = (ushort*)d_ws;
  ushort* w2l  = w2h + 65536;
  ushort* w3h  = w2l + 65536;
  ushort* w3l  = w3h + 8192;
  ushort* w1eh = w3l + 8192;
  ushort* w1el = w1eh + 24576;
  ushort* w2eh = w1el + 24576;
  ushort* w2el = w2eh + 16384;
  ushort* pair_h = w2el + 16384;
  ushort* pair_l = pair_h + (size_t)E_EDGES * 32;
  ushort* f_h    = pair_l + (size_t)E_EDGES * 32;
  ushort* f_l    = f_h + (size_t)N_DETS * 32;
  float* f  = (float*)(f_l + (size_t)N_DETS * 32);
  float* m  = f  + (size_t)N_DETS * 32;
  float* mm = m  + (size_t)N_DETS * 64;
  float* xa = mm + (size_t)N_DETS * 64;
  float* xb = xa + (size_t)N_DETS * 128;

  hipMemcpyAsync(xa, detF, (size_t)N_DETS * 128 * sizeof(float),
                 hipMemcpyDeviceToDevice, stream);

  split_w_kernel<<<256, 256, 0, stream>>>(gW2, w2h, w2l, 256);
  split_w_kernel<<<32, 256, 0, stream>>>(gW3, w3h, w3l, 32);
  split_edge_w_kernel<<<4, 256, 0, stream>>>(pwW1, pwW2, w1eh, w1el, w2eh, w2el);

  pair_mlp_kernel<<<256, 1024, 0, stream>>>(pairRaw, gW1, gb1,
      w2h, w2l, gb2, w3h, w3l, gb3, pair_h, pair_l);

  float* xin = xa;
  float* xout = xb;
  for (int b = 0; b < 4; ++b) {
    fc1_kernel<<<N_DETS / 8, 256, 0, stream>>>(xin, fc1W + b * 4096, fc1b + b * 32,
        f, f_h, f_l);
    edge_kernel<<<EDGE_GRID, 512, 0, stream>>>(pair_h, pair_l, f, f_h, f_l, nIdx,
        pwW1 + b * 6144, pwb1 + b * 64,
        w1eh + b * 6144, w1el + b * 6144, w2eh + b * 4096, w2el + b * 4096,
        pwb2 + b * 64, m);
    post_fused_kernel<<<N_DETS / 32, 256, 0, stream>>>(m, xin,
        poW1 + b * 4096, pob1 + b * 64, poW2 + b * 4096, pob2 + b * 64,
        outW + b * 8192, outb + b * 128, xout);
    float* tmp = xout; xout = xin; xin = tmp;
  }
  for (int i = 0; i < 3; ++i) {
    score_layer_kernel<<<N_DETS / 16, 256, 0, stream>>>(xin, sW + i * 16384, sb + i * 128, xout);
    float* tmp = xout; xout = xin; xin = tmp;
  }
  dot_kernel<<<N_DETS / 4, 256, 0, stream>>>(xin, predW, predb, out);
}

// Round 18
// 724.313 us; speedup vs baseline: 1.4547x; 1.1740x over previous
//
#include <hip/hip_runtime.h>

// R18: third submission of the R16 kernel (two consecutive UnresponsiveContainer
// failures; code has never executed). pair_mlp = R13 exact; score head = one
// persistent split-bf16 MFMA kernel replacing 3x score_layer + dot.
#define N_DETS 16384
#define DEG 32
#define E_EDGES (N_DETS * DEG)   // 524288
#define EDGE_GRID 512

typedef __attribute__((ext_vector_type(8))) short bf16x8;
typedef __attribute__((ext_vector_type(4))) float f32x4;

__device__ __forceinline__ ushort f32_to_bf16(float v) {
  unsigned u = __float_as_uint(v);
  u += 0x7FFFu + ((u >> 16) & 1u);    // round-to-nearest-even
  return (ushort)(u >> 16);
}
__device__ __forceinline__ float bf16_to_f32(ushort h) {
  return __uint_as_float((unsigned)h << 16);
}

// ============ prep: out[n][k] = split_hi/lo(W[k][n]); K==256, grid=N ============
__global__ __launch_bounds__(256) void split_w_kernel(
    const float* __restrict__ W, ushort* __restrict__ hi, ushort* __restrict__ lo, int N)
{
  const int n = blockIdx.x, k = threadIdx.x;
  const float v = W[(size_t)k * N + n];
  const ushort h = f32_to_bf16(v);
  const ushort l = f32_to_bf16(v - bf16_to_f32(h));
  hi[(size_t)n * 256 + k] = h;
  lo[(size_t)n * 256 + k] = l;
}

// ============ prep: edge-block W1 (96x64) + W2 (64x64) -> [col][k] split ============
__global__ __launch_bounds__(256) void split_edge_w_kernel(
    const float* __restrict__ W1all, const float* __restrict__ W2all,
    ushort* __restrict__ w1h, ushort* __restrict__ w1l,
    ushort* __restrict__ w2h, ushort* __restrict__ w2l)
{
  const int b = blockIdx.x;
  const float* W1 = W1all + b * 6144;
  const float* W2 = W2all + b * 4096;
  for (int i = threadIdx.x; i < 6144; i += 256) {
    const int col = i / 96, k = i % 96;
    const float v = W1[k * 64 + col];
    const ushort h = f32_to_bf16(v);
    w1h[b * 6144 + col * 96 + k] = h;
    w1l[b * 6144 + col * 96 + k] = f32_to_bf16(v - bf16_to_f32(h));
  }
  for (int i = threadIdx.x; i < 4096; i += 256) {
    const int col = i >> 6, k = i & 63;
    const float v = W2[k * 64 + col];
    const ushort h = f32_to_bf16(v);
    w2h[b * 4096 + col * 64 + k] = h;
    w2l[b * 4096 + col * 64 + k] = f32_to_bf16(v - bf16_to_f32(h));
  }
}

// ============ prep: score sW (3x128x128) -> [layer][col][k] split ============
__global__ __launch_bounds__(128) void split_score_w_kernel(
    const float* __restrict__ sW, ushort* __restrict__ hi, ushort* __restrict__ lo)
{
  const int layer = blockIdx.x >> 7, col = blockIdx.x & 127, k = threadIdx.x;
  const float v = sW[layer * 16384 + k * 128 + col];
  const ushort h = f32_to_bf16(v);
  hi[layer * 16384 + col * 128 + k] = h;
  lo[layer * 16384 + col * 128 + k] = f32_to_bf16(v - bf16_to_f32(h));
}

// ===================== pairwise MLP: 9 -> 256 -> 256 -> 32 (R13 exact) =====================
#define A_STRIDE 264

__global__ __launch_bounds__(1024, 4) void pair_mlp_kernel(
    const float* __restrict__ raw,
    const float* __restrict__ W1, const float* __restrict__ b1,
    const ushort* __restrict__ w2h, const ushort* __restrict__ w2l,
    const float* __restrict__ b2,
    const ushort* __restrict__ w3h, const ushort* __restrict__ w3l,
    const float* __restrict__ b3,
    ushort* __restrict__ pair_h, ushort* __restrict__ pair_l)
{
  __shared__ __align__(16) ushort ah[64 * A_STRIDE];    // 33.8 KB (h1 then h2)
  __shared__ __align__(16) ushort al[64 * A_STRIDE];    // 33.8 KB
  __shared__ __align__(16) ushort w3sh[32 * A_STRIDE];  // 16.9 KB
  __shared__ __align__(16) ushort w3sl[32 * A_STRIDE];  // 16.9 KB
  __shared__ __align__(16) float rawt[64 * 12];         // 3 KB  => 104.4 KB

  const int t = threadIdx.x;
  const int lane = t & 63, wv = t >> 6;    // 16 waves
  const int ln = lane & 15, kg = lane >> 4;

  for (int i = t; i < 32 * 64; i += 1024) {
    const int row = (i * 4) >> 8, col = (i * 4) & 255;
    *(ushort4*)&w3sh[row * A_STRIDE + col] = *(const ushort4*)&w3h[row * 256 + col];
    *(ushort4*)&w3sl[row * A_STRIDE + col] = *(const ushort4*)&w3l[row * 256 + col];
  }

  bf16x8 b2hreg[8], b2lreg[8];
  #pragma unroll
  for (int ks = 0; ks < 8; ++ks) {
    const size_t bo = (size_t)(wv * 16 + ln) * 256 + ks * 32 + kg * 8;
    b2hreg[ks] = *(const bf16x8*)&w2h[bo];
    b2lreg[ks] = *(const bf16x8*)&w2l[bo];
  }
  const float bias2 = b2[wv * 16 + ln];
  const int mt3 = (wv >> 1) & 3, nt3 = wv & 1;
  const float b3v = b3[nt3 * 16 + ln];
  __syncthreads();

  for (int grp = blockIdx.x; grp < E_EDGES / 64; grp += gridDim.x) {
    const long long e0 = (long long)grp * 64;

    if (t < 64 * 9) rawt[(t / 9) * 12 + (t % 9)] = raw[e0 * 9 + t];
    __syncthreads();

    {
      const int col = t & 255, r0 = (t >> 8) * 16;
      const float bv = b1[col];
      float wk[9];
      #pragma unroll
      for (int k = 0; k < 9; ++k) wk[k] = W1[k * 256 + col];
      #pragma unroll
      for (int r = 0; r < 16; ++r) {
        const int row = r0 + r;
        const float4 ra = *(const float4*)&rawt[row * 12];
        const float4 rb = *(const float4*)&rawt[row * 12 + 4];
        const float rc = rawt[row * 12 + 8];
        float s = bv;
        s = fmaf(ra.x, wk[0], s); s = fmaf(ra.y, wk[1], s);
        s = fmaf(ra.z, wk[2], s); s = fmaf(ra.w, wk[3], s);
        s = fmaf(rb.x, wk[4], s); s = fmaf(rb.y, wk[5], s);
        s = fmaf(rb.z, wk[6], s); s = fmaf(rb.w, wk[7], s);
        s = fmaf(rc, wk[8], s);
        const float v = fmaxf(s, 0.f);
        const ushort h = f32_to_bf16(v);
        ah[row * A_STRIDE + col] = h;
        al[row * A_STRIDE + col] = f32_to_bf16(v - bf16_to_f32(h));
      }
    }
    __syncthreads();

    f32x4 acc[4];
    #pragma unroll
    for (int mt = 0; mt < 4; ++mt) {
      acc[mt][0] = 0.f; acc[mt][1] = 0.f; acc[mt][2] = 0.f; acc[mt][3] = 0.f;
    }
    #pragma unroll
    for (int ks = 0; ks < 8; ++ks) {
      const int ka = ks * 32 + kg * 8;
      #pragma unroll
      for (int mt = 0; mt < 4; ++mt) {
        const bf16x8 ahf = *(const bf16x8*)&ah[(mt * 16 + ln) * A_STRIDE + ka];
        const bf16x8 alf = *(const bf16x8*)&al[(mt * 16 + ln) * A_STRIDE + ka];
        acc[mt] = __builtin_amdgcn_mfma_f32_16x16x32_bf16(ahf, b2hreg[ks], acc[mt], 0, 0, 0);
        acc[mt] = __builtin_amdgcn_mfma_f32_16x16x32_bf16(alf, b2hreg[ks], acc[mt], 0, 0, 0);
        acc[mt] = __builtin_amdgcn_mfma_f32_16x16x32_bf16(ahf, b2lreg[ks], acc[mt], 0, 0, 0);
      }
    }
    __syncthreads();

    {
      const int colg = wv * 16 + ln;
      #pragma unroll
      for (int mt = 0; mt < 4; ++mt)
        #pragma unroll
        for (int r = 0; r < 4; ++r) {
          const int rowe = mt * 16 + kg * 4 + r;
          const float v = fmaxf(acc[mt][r] + bias2, 0.f);
          const ushort h = f32_to_bf16(v);
          ah[rowe * A_STRIDE + colg] = h;
          al[rowe * A_STRIDE + colg] = f32_to_bf16(v - bf16_to_f32(h));
        }
    }
    __syncthreads();

    if (wv < 8) {
      f32x4 acc3;
      acc3[0] = 0.f; acc3[1] = 0.f; acc3[2] = 0.f; acc3[3] = 0.f;
      #pragma unroll
      for (int ks = 0; ks < 8; ++ks) {
        const int ka = ks * 32 + kg * 8;
        const bf16x8 a_h = *(const bf16x8*)&ah[(mt3 * 16 + ln) * A_STRIDE + ka];
        const bf16x8 a_l = *(const bf16x8*)&al[(mt3 * 16 + ln) * A_STRIDE + ka];
        const bf16x8 b_h = *(const bf16x8*)&w3sh[(nt3 * 16 + ln) * A_STRIDE + ka];
        const bf16x8 b_l = *(const bf16x8*)&w3sl[(nt3 * 16 + ln) * A_STRIDE + ka];
        acc3 = __builtin_amdgcn_mfma_f32_16x16x32_bf16(a_h, b_h, acc3, 0, 0, 0);
        acc3 = __builtin_amdgcn_mfma_f32_16x16x32_bf16(a_l, b_h, acc3, 0, 0, 0);
        acc3 = __builtin_amdgcn_mfma_f32_16x16x32_bf16(a_h, b_l, acc3, 0, 0, 0);
      }
      const int col3 = nt3 * 16 + ln;
      #pragma unroll
      for (int r = 0; r < 4; ++r) {
        const int rowe = mt3 * 16 + kg * 4 + r;
        const float v = fmaxf(acc3[r] + b3v, 0.f);
        const ushort h = f32_to_bf16(v);
        const size_t idx = (size_t)(e0 + rowe) * 32 + col3;
        pair_h[idx] = h;
        pair_l[idx] = f32_to_bf16(v - bf16_to_f32(h));
      }
    }
    __syncthreads();
  }
}

// ========== f = relu(x @ fc1_W + b) : (N,128)@(128,32); emits f32 + split ==========
__global__ __launch_bounds__(256) void fc1_kernel(
    const float* __restrict__ x, const float* __restrict__ W,
    const float* __restrict__ b, float* __restrict__ f,
    ushort* __restrict__ f_h, ushort* __restrict__ f_l)
{
  __shared__ float Wl[128 * 32];
  const int t = threadIdx.x;
  #pragma unroll
  for (int j = 0; j < 4; ++j) {
    const int off = t * 4 + j * 1024;
    *(float4*)&Wl[off] = *(const float4*)&W[off];
  }
  __syncthreads();
  const int c = t & 31, rr = t >> 5;
  const long long r = (long long)blockIdx.x * 8 + rr;
  const float* xr = x + r * 128;
  float acc = b[c];
  #pragma unroll 8
  for (int k = 0; k < 128; k += 4) {
    const float4 a = *(const float4*)&xr[k];
    acc = fmaf(a.x, Wl[(k + 0) * 32 + c], acc);
    acc = fmaf(a.y, Wl[(k + 1) * 32 + c], acc);
    acc = fmaf(a.z, Wl[(k + 2) * 32 + c], acc);
    acc = fmaf(a.w, Wl[(k + 3) * 32 + c], acc);
  }
  const float v = fmaxf(acc, 0.f);
  f[r * 32 + c] = v;
  const ushort h = f32_to_bf16(v);
  f_h[r * 32 + c] = h;
  f_l[r * 32 + c] = f32_to_bf16(v - bf16_to_f32(h));
}

// ====== edge MLP (96->64->64) + segment-max, split-bf16 MFMA, persistent ======
#define W1S 104
#define W2S 72
#define CTS 36

__global__ __launch_bounds__(512, 2) void edge_kernel(
    const ushort* __restrict__ pair_h, const ushort* __restrict__ pair_l,
    const float* __restrict__ f,
    const ushort* __restrict__ f_h, const ushort* __restrict__ f_l,
    const int* __restrict__ nIdxs,
    const float* __restrict__ W1g, const float* __restrict__ bb1,
    const ushort* __restrict__ gw1h, const ushort* __restrict__ gw1l,
    const ushort* __restrict__ gw2h, const ushort* __restrict__ gw2l,
    const float* __restrict__ bb2,
    float* __restrict__ m)
{
  __shared__ __align__(16) ushort W1hS[64 * W1S], W1lS[64 * W1S];
  __shared__ __align__(16) ushort W2hS[64 * W2S], W2lS[64 * W2S];
  __shared__ __align__(16) float  W1cT[64 * CTS];
  __shared__ __align__(16) ushort h1h[8][32 * W2S], h1l[8][32 * W2S];

  const int t = threadIdx.x;
  const int lane = t & 63, wv = t >> 6;
  const int ln = lane & 15, kg = lane >> 4;

  for (int i = t; i < 1536; i += 512) {
    const int idx = i * 4, row = idx / 96, k = idx % 96;
    *(ushort4*)&W1hS[row * W1S + k] = *(const ushort4*)&gw1h[idx];
    *(ushort4*)&W1lS[row * W1S + k] = *(const ushort4*)&gw1l[idx];
  }
  for (int i = t; i < 1024; i += 512) {
    const int idx = i * 4, row = idx >> 6, k = idx & 63;
    *(ushort4*)&W2hS[row * W2S + k] = *(const ushort4*)&gw2h[idx];
    *(ushort4*)&W2lS[row * W2S + k] = *(const ushort4*)&gw2l[idx];
  }
  for (int i = t; i < 2048; i += 512) {
    const int col = i >> 5, j = i & 31;
    W1cT[col * CTS + j] = W1g[(32 + j) * 64 + col];
  }
  __syncthreads();

  for (int dg = blockIdx.x; dg < N_DETS / 8; dg += gridDim.x) {
    const int d = dg * 8 + wv;
    const long long e0 = (long long)d * 32;

    float cfs[4];
    {
      const float4 fv0 = *(const float4*)&f[(size_t)d * 32 + kg * 8];
      const float4 fv1 = *(const float4*)&f[(size_t)d * 32 + kg * 8 + 4];
      #pragma unroll
      for (int nt = 0; nt < 4; ++nt) {
        const int col = nt * 16 + ln;
        const float4 w0 = *(const float4*)&W1cT[col * CTS + kg * 8];
        const float4 w1 = *(const float4*)&W1cT[col * CTS + kg * 8 + 4];
        float s = fv0.x * w0.x + fv0.y * w0.y + fv0.z * w0.z + fv0.w * w0.w
                + fv1.x * w1.x + fv1.y * w1.y + fv1.z * w1.z + fv1.w * w1.w;
        s += __shfl_xor(s, 16);
        s += __shfl_xor(s, 32);
        cfs[nt] = s + bb1[col];
      }
    }

    f32x4 acc1[4][2];
    #pragma unroll
    for (int nt = 0; nt < 4; ++nt)
      #pragma unroll
      for (int mt = 0; mt < 2; ++mt) {
        acc1[nt][mt][0] = 0.f; acc1[nt][mt][1] = 0.f;
        acc1[nt][mt][2] = 0.f; acc1[nt][mt][3] = 0.f;
      }
    bf16x8 ph[2], pl_[2], nh[2], nl_[2];
    #pragma unroll
    for (int mt = 0; mt < 2; ++mt) {
      const long long row = e0 + mt * 16 + ln;
      ph[mt]  = *(const bf16x8*)&pair_h[row * 32 + kg * 8];
      pl_[mt] = *(const bf16x8*)&pair_l[row * 32 + kg * 8];
      const int n = nIdxs[row];
      bf16x8 vh = *(const bf16x8*)&f_h[(size_t)n * 32 + kg * 8];
      bf16x8 vl = *(const bf16x8*)&f_l[(size_t)n * 32 + kg * 8];
      if (n == d) { vh = (bf16x8){0,0,0,0,0,0,0,0}; vl = (bf16x8){0,0,0,0,0,0,0,0}; }
      nh[mt] = vh; nl_[mt] = vl;
    }
    #pragma unroll
    for (int nt = 0; nt < 4; ++nt) {
      const int bro = (nt * 16 + ln) * W1S;
      const bf16x8 b0h = *(const bf16x8*)&W1hS[bro + kg * 8];
      const bf16x8 b0l = *(const bf16x8*)&W1lS[bro + kg * 8];
      const bf16x8 b1h = *(const bf16x8*)&W1hS[bro + 64 + kg * 8];
      const bf16x8 b1l = *(const bf16x8*)&W1lS[bro + 64 + kg * 8];
      #pragma unroll
      for (int mt = 0; mt < 2; ++mt) {
        acc1[nt][mt] = __builtin_amdgcn_mfma_f32_16x16x32_bf16(ph[mt], b0h, acc1[nt][mt], 0, 0, 0);
        acc1[nt][mt] = __builtin_amdgcn_mfma_f32_16x16x32_bf16(pl_[mt], b0h, acc1[nt][mt], 0, 0, 0);
        acc1[nt][mt] = __builtin_amdgcn_mfma_f32_16x16x32_bf16(ph[mt], b0l, acc1[nt][mt], 0, 0, 0);
        acc1[nt][mt] = __builtin_amdgcn_mfma_f32_16x16x32_bf16(nh[mt], b1h, acc1[nt][mt], 0, 0, 0);
        acc1[nt][mt] = __builtin_amdgcn_mfma_f32_16x16x32_bf16(nl_[mt], b1h, acc1[nt][mt], 0, 0, 0);
        acc1[nt][mt] = __builtin_amdgcn_mfma_f32_16x16x32_bf16(nh[mt], b1l, acc1[nt][mt], 0, 0, 0);
      }
    }

    #pragma unroll
    for (int nt = 0; nt < 4; ++nt) {
      const int col = nt * 16 + ln;
      #pragma unroll
      for (int mt = 0; mt < 2; ++mt)
        #pragma unroll
        for (int r = 0; r < 4; ++r) {
          const int row = mt * 16 + kg * 4 + r;
          const float v = fmaxf(acc1[nt][mt][r] + cfs[nt], 0.f);
          const ushort h = f32_to_bf16(v);
          h1h[wv][row * W2S + col] = h;
          h1l[wv][row * W2S + col] = f32_to_bf16(v - bf16_to_f32(h));
        }
    }

    f32x4 acc2[4][2];
    #pragma unroll
    for (int mt = 0; mt < 4; ++mt)
      #pragma unroll
      for (int nt = 0; nt < 2; ++nt) {
        acc2[mt][nt][0] = 0.f; acc2[mt][nt][1] = 0.f;
        acc2[mt][nt][2] = 0.f; acc2[mt][nt][3] = 0.f;
      }
    #pragma unroll
    for (int ks = 0; ks < 2; ++ks) {
      const int ka = ks * 32 + kg * 8;
      bf16x8 bh[2], bl[2];
      #pragma unroll
      for (int nt = 0; nt < 2; ++nt) {
        bh[nt] = *(const bf16x8*)&h1h[wv][(nt * 16 + ln) * W2S + ka];
        bl[nt] = *(const bf16x8*)&h1l[wv][(nt * 16 + ln) * W2S + ka];
      }
      #pragma unroll
      for (int mt = 0; mt < 4; ++mt) {
        const bf16x8 a_h = *(const bf16x8*)&W2hS[(mt * 16 + ln) * W2S + ka];
        const bf16x8 a_l = *(const bf16x8*)&W2lS[(mt * 16 + ln) * W2S + ka];
        #pragma unroll
        for (int nt = 0; nt < 2; ++nt) {
          acc2[mt][nt] = __builtin_amdgcn_mfma_f32_16x16x32_bf16(a_h, bh[nt], acc2[mt][nt], 0, 0, 0);
          acc2[mt][nt] = __builtin_amdgcn_mfma_f32_16x16x32_bf16(a_h, bl[nt], acc2[mt][nt], 0, 0, 0);
          acc2[mt][nt] = __builtin_amdgcn_mfma_f32_16x16x32_bf16(a_l, bh[nt], acc2[mt][nt], 0, 0, 0);
        }
      }
    }

    #pragma unroll
    for (int mt = 0; mt < 4; ++mt)
      #pragma unroll
      for (int r = 0; r < 4; ++r) {
        float mx = fmaxf(acc2[mt][0][r], acc2[mt][1][r]);
        mx = fmaxf(mx, __shfl_xor(mx, 1));
        mx = fmaxf(mx, __shfl_xor(mx, 2));
        mx = fmaxf(mx, __shfl_xor(mx, 4));
        mx = fmaxf(mx, __shfl_xor(mx, 8));
        if (ln == mt * 4 + r) {
          const int outcol = mt * 16 + kg * 4 + r;
          m[(size_t)d * 64 + outcol] = fmaxf(mx + bb2[outcol], 0.f);
        }
      }
  }
}

// ==== fused post: y = relu(x + relu(relu(m@W1+b1)@W2+b2) @ Wo + bo), 32 rows/blk ====
__global__ __launch_bounds__(256) void post_fused_kernel(
    const float* __restrict__ m, const float* __restrict__ x,
    const float* __restrict__ W1, const float* __restrict__ b1,
    const float* __restrict__ W2, const float* __restrict__ b2,
    const float* __restrict__ Wo, const float* __restrict__ bo,
    float* __restrict__ y)
{
  __shared__ float Wl[64 * 64];
  __shared__ float Wlo[64 * 128];
  __shared__ float mt[32 * 64];
  __shared__ float ht[32 * 64];
  const int t = threadIdx.x;
  const int c = t & 63, g = t >> 6;
  const long long r0 = (long long)blockIdx.x * 32;
  #pragma unroll
  for (int j = 0; j < 4; ++j) {
    const int off = t * 4 + j * 1024;
    *(float4*)&Wl[off] = *(const float4*)&W1[off];
  }
  #pragma unroll
  for (int j = 0; j < 8; ++j) {
    const int off = t * 4 + j * 1024;
    *(float4*)&Wlo[off] = *(const float4*)&Wo[off];
  }
  #pragma unroll
  for (int j = 0; j < 2; ++j) {
    const int off = t * 4 + j * 1024;
    *(float4*)&mt[off] = *(const float4*)&m[r0 * 64 + off];
  }
  __syncthreads();
  float acc[8];
  {
    const float bv = b1[c];
    #pragma unroll
    for (int i = 0; i < 8; ++i) acc[i] = bv;
  }
  #pragma unroll 4
  for (int k = 0; k < 64; k += 4) {
    const float w0 = Wl[(k + 0) * 64 + c], w1 = Wl[(k + 1) * 64 + c];
    const float w2 = Wl[(k + 2) * 64 + c], w3 = Wl[(k + 3) * 64 + c];
    #pragma unroll
    for (int i = 0; i < 8; ++i) {
      const float4 a = *(const float4*)&mt[(g * 8 + i) * 64 + k];
      acc[i] = fmaf(a.x, w0, fmaf(a.y, w1, fmaf(a.z, w2, fmaf(a.w, w3, acc[i]))));
    }
  }
  #pragma unroll
  for (int i = 0; i < 8; ++i) ht[(g * 8 + i) * 64 + c] = fmaxf(acc[i], 0.f);
  __syncthreads();
  #pragma unroll
  for (int j = 0; j < 4; ++j) {
    const int off = t * 4 + j * 1024;
    *(float4*)&Wl[off] = *(const float4*)&W2[off];
  }
  __syncthreads();
  float acc2[8];
  {
    const float bv = b2[c];
    #pragma unroll
    for (int i = 0; i < 8; ++i) acc2[i] = bv;
  }
  #pragma unroll 4
  for (int k = 0; k < 64; k += 4) {
    const float w0 = Wl[(k + 0) * 64 + c], w1 = Wl[(k + 1) * 64 + c];
    const float w2 = Wl[(k + 2) * 64 + c], w3 = Wl[(k + 3) * 64 + c];
    #pragma unroll
    for (int i = 0; i < 8; ++i) {
      const float4 a = *(const float4*)&ht[(g * 8 + i) * 64 + k];
      acc2[i] = fmaf(a.x, w0, fmaf(a.y, w1, fmaf(a.z, w2, fmaf(a.w, w3, acc2[i]))));
    }
  }
  #pragma unroll
  for (int i = 0; i < 8; ++i) mt[(g * 8 + i) * 64 + c] = fmaxf(acc2[i], 0.f);
  __syncthreads();
  const int c2 = t & 127, g2 = t >> 7;
  float acco[16];
  {
    const float bv = bo[c2];
    #pragma unroll
    for (int i = 0; i < 16; ++i) acco[i] = bv;
  }
  #pragma unroll 4
  for (int k = 0; k < 64; k += 4) {
    const float w0 = Wlo[(k + 0) * 128 + c2], w1 = Wlo[(k + 1) * 128 + c2];
    const float w2 = Wlo[(k + 2) * 128 + c2], w3 = Wlo[(k + 3) * 128 + c2];
    #pragma unroll
    for (int i = 0; i < 16; ++i) {
      const float4 a = *(const float4*)&mt[(g2 * 16 + i) * 64 + k];
      acco[i] = fmaf(a.x, w0, fmaf(a.y, w1, fmaf(a.z, w2, fmaf(a.w, w3, acco[i]))));
    }
  }
  #pragma unroll
  for (int i = 0; i < 16; ++i) {
    const long long idx = (r0 + g2 * 16 + i) * 128 + c2;
    y[idx] = fmaxf(x[idx] + acco[i], 0.f);
  }
}

// ====== score head: 3x (128->128 relu) + dot, split-bf16 MFMA, 32 rows/block ======
#define XS 136   // LDS ushort/float stride for [32][128] tiles

__global__ __launch_bounds__(512) void score_head_kernel(
    const float* __restrict__ x,
    const ushort* __restrict__ swh, const ushort* __restrict__ swl,
    const float* __restrict__ sb,
    const float* __restrict__ pW, const float* __restrict__ pb,
    float* __restrict__ out)
{
  __shared__ __align__(16) ushort xh[2][32 * XS], xl[2][32 * XS];  // 34.8 KB
  __shared__ __align__(16) float hsf[32 * XS];                    // 17.4 KB
  __shared__ float pWs[128];
  const int t = threadIdx.x;
  const int lane = t & 63, wv = t >> 6;
  const int ln = lane & 15, kg = lane >> 4;
  const long long r0 = (long long)blockIdx.x * 32;

  if (t < 128) pWs[t] = pW[t];
  for (int i = t; i < 32 * 32; i += 512) {          // 4 elems/thread via float4
    const int row = i >> 5, cq = (i & 31) * 4;
    const float4 v4 = *(const float4*)&x[(r0 + row) * 128 + cq];
    const float vv[4] = {v4.x, v4.y, v4.z, v4.w};
    #pragma unroll
    for (int j = 0; j < 4; ++j) {
      const ushort h = f32_to_bf16(vv[j]);
      xh[0][row * XS + cq + j] = h;
      xl[0][row * XS + cq + j] = f32_to_bf16(vv[j] - bf16_to_f32(h));
    }
  }
  __syncthreads();

  const int colg = wv * 16 + ln;
  int cur = 0;
  #pragma unroll 1
  for (int layer = 0; layer < 3; ++layer) {
    const ushort* wh = swh + (size_t)layer * 16384 + (size_t)colg * 128;
    const ushort* wl = swl + (size_t)layer * 16384 + (size_t)colg * 128;
    f32x4 acc[2];
    #pragma unroll
    for (int mt = 0; mt < 2; ++mt) {
      acc[mt][0] = 0.f; acc[mt][1] = 0.f; acc[mt][2] = 0.f; acc[mt][3] = 0.f;
    }
    #pragma unroll
    for (int ks = 0; ks < 4; ++ks) {
      const int ka = ks * 32 + kg * 8;
      const bf16x8 b_h = *(const bf16x8*)&wh[ka];
      const bf16x8 b_l = *(const bf16x8*)&wl[ka];
      #pragma unroll
      for (int mt = 0; mt < 2; ++mt) {
        const bf16x8 a_h = *(const bf16x8*)&xh[cur][(mt * 16 + ln) * XS + ka];
        const bf16x8 a_l = *(const bf16x8*)&xl[cur][(mt * 16 + ln) * XS + ka];
        acc[mt] = __builtin_amdgcn_mfma_f32_16x16x32_bf16(a_h, b_h, acc[mt], 0, 0, 0);
        acc[mt] = __builtin_amdgcn_mfma_f32_16x16x32_bf16(a_l, b_h, acc[mt], 0, 0, 0);
        acc[mt] = __builtin_amdgcn_mfma_f32_16x16x32_bf16(a_h, b_l, acc[mt], 0, 0, 0);
      }
    }
    const float bias = sb[layer * 128 + colg];
    __syncthreads();   // all reads of xh[cur] done before overwrite targets used
    if (layer < 2) {
      #pragma unroll
      for (int mt = 0; mt < 2; ++mt)
        #pragma unroll
        for (int r = 0; r < 4; ++r) {
          const int row = mt * 16 + kg * 4 + r;
          const float v = fmaxf(acc[mt][r] + bias, 0.f);
          const ushort h = f32_to_bf16(v);
          xh[cur ^ 1][row * XS + colg] = h;
          xl[cur ^ 1][row * XS + colg] = f32_to_bf16(v - bf16_to_f32(h));
        }
      cur ^= 1;
    } else {
      #pragma unroll
      for (int mt = 0; mt < 2; ++mt)
        #pragma unroll
        for (int r = 0; r < 4; ++r) {
          const int row = mt * 16 + kg * 4 + r;
          hsf[row * XS + colg] = fmaxf(acc[mt][r] + bias, 0.f);
        }
    }
    __syncthreads();
  }

  // dot: 16 threads per row
  {
    const int row = t >> 4, l16 = t & 15;
    const float4 a0 = *(const float4*)&hsf[row * XS + l16 * 8];
    const float4 a1 = *(const float4*)&hsf[row * XS + l16 * 8 + 4];
    const float4 w0 = *(const float4*)&pWs[l16 * 8];
    const float4 w1 = *(const float4*)&pWs[l16 * 8 + 4];
    float s = a0.x * w0.x + a0.y * w0.y + a0.z * w0.z + a0.w * w0.w
            + a1.x * w1.x + a1.y * w1.y + a1.z * w1.z + a1.w * w1.w;
    s += __shfl_xor(s, 1);
    s += __shfl_xor(s, 2);
    s += __shfl_xor(s, 4);
    s += __shfl_xor(s, 8);
    if (l16 == 0) out[r0 + row] = s + pb[0];
  }
}

extern "C" void kernel_launch(void* const* d_in, const int* in_sizes, int n_in,
                              void* d_out, int out_size, void* d_ws, size_t ws_size,
                              hipStream_t stream)
{
  const float* detF    = (const float*)d_in[0];
  const float* pairRaw = (const float*)d_in[1];
  const int*   cIdx    = (const int*)d_in[2];
  const int*   nIdx    = (const int*)d_in[3];
  const float* gW1 = (const float*)d_in[4];   const float* gb1 = (const float*)d_in[5];
  const float* gW2 = (const float*)d_in[6];   const float* gb2 = (const float*)d_in[7];
  const float* gW3 = (const float*)d_in[8];   const float* gb3 = (const float*)d_in[9];
  const float* fc1W = (const float*)d_in[10]; const float* fc1b = (const float*)d_in[11];
  const float* pwW1 = (const float*)d_in[12]; const float* pwb1 = (const float*)d_in[13];
  const float* pwW2 = (const float*)d_in[14]; const float* pwb2 = (const float*)d_in[15];
  const float* poW1 = (const float*)d_in[16]; const float* pob1 = (const float*)d_in[17];
  const float* poW2 = (const float*)d_in[18]; const float* pob2 = (const float*)d_in[19];
  const float* outW = (const float*)d_in[20]; const float* outb = (const float*)d_in[21];
  const float* sW = (const float*)d_in[22];   const float* sb = (const float*)d_in[23];
  const float* predW = (const float*)d_in[24]; const float* predb = (const float*)d_in[25];
  float* out = (float*)d_out;
  (void)cIdx;   // cIdxs == repeat(arange(N), DEG) per setup; d = e >> 5

  ushort* w2h  = (ushort*)d_ws;
  ushort* w2l  = w2h + 65536;
  ushort* w3h  = w2l + 65536;
  ushort* w3l  = w3h + 8192;
  ushort* w1eh = w3l + 8192;
  ushort* w1el = w1eh + 24576;
  ushort* w2eh = w1el + 24576;
  ushort* w2el = w2eh + 16384;
  ushort* swh  = w2el + 16384;                 // 3*16384
  ushort* swl  = swh + 49152;
  ushort* pair_h = swl + 49152;
  ushort* pair_l = pair_h + (size_t)E_EDGES * 32;
  ushort* f_h    = pair_l + (size_t)E_EDGES * 32;
  ushort* f_l    = f_h + (size_t)N_DETS * 32;
  float* f  = (float*)(f_l + (size_t)N_DETS * 32);
  float* m  = f  + (size_t)N_DETS * 32;
  float* mm = m  + (size_t)N_DETS * 64;
  float* xa = mm + (size_t)N_DETS * 64;
  float* xb = xa + (size_t)N_DETS * 128;

  hipMemcpyAsync(xa, detF, (size_t)N_DETS * 128 * sizeof(float),
                 hipMemcpyDeviceToDevice, stream);

  split_w_kernel<<<256, 256, 0, stream>>>(gW2, w2h, w2l, 256);
  split_w_kernel<<<32, 256, 0, stream>>>(gW3, w3h, w3l, 32);
  split_edge_w_kernel<<<4, 256, 0, stream>>>(pwW1, pwW2, w1eh, w1el, w2eh, w2el);
  split_score_w_kernel<<<384, 128, 0, stream>>>(sW, swh, swl);

  pair_mlp_kernel<<<256, 1024, 0, stream>>>(pairRaw, gW1, gb1,
      w2h, w2l, gb2, w3h, w3l, gb3, pair_h, pair_l);

  float* xin = xa;
  float* xout = xb;
  for (int b = 0; b < 4; ++b) {
    fc1_kernel<<<N_DETS / 8, 256, 0, stream>>>(xin, fc1W + b * 4096, fc1b + b * 32,
        f, f_h, f_l);
    edge_kernel<<<EDGE_GRID, 512, 0, stream>>>(pair_h, pair_l, f, f_h, f_l, nIdx,
        pwW1 + b * 6144, pwb1 + b * 64,
        w1eh + b * 6144, w1el + b * 6144, w2eh + b * 4096, w2el + b * 4096,
        pwb2 + b * 64, m);
    post_fused_kernel<<<N_DETS / 32, 256, 0, stream>>>(m, xin,
        poW1 + b * 4096, pob1 + b * 64, poW2 + b * 4096, pob2 + b * 64,
        outW + b * 8192, outb + b * 128, xout);
    float* tmp = xout; xout = xin; xin = tmp;
  }
  score_head_kernel<<<N_DETS / 32, 512, 0, stream>>>(xin, swh, swl, sb,
      predW, predb, out);
}

// Round 21
// 678.203 us; speedup vs baseline: 1.5536x; 1.0680x over previous
//
#include <hip/hip_runtime.h>

// R21: fourth submission of the R19 kernel (three consecutive
// UnresponsiveContainer failures; code has never executed).
// R19: fuse post12+postout+next-block-fc1 into ONE split-bf16 MFMA kernel
// (postfc1). Removes 3 fc1 launches, 4 fp32-VALU post launches, and a
// y global round-trip. pair_mlp/edge/score_head unchanged from R18
// (724us, absmax 6.1e-5).
#define N_DETS 16384
#define DEG 32
#define E_EDGES (N_DETS * DEG)   // 524288
#define EDGE_GRID 512

typedef __attribute__((ext_vector_type(8))) short bf16x8;
typedef __attribute__((ext_vector_type(4))) float f32x4;

__device__ __forceinline__ ushort f32_to_bf16(float v) {
  unsigned u = __float_as_uint(v);
  u += 0x7FFFu + ((u >> 16) & 1u);    // round-to-nearest-even
  return (ushort)(u >> 16);
}
__device__ __forceinline__ float bf16_to_f32(ushort h) {
  return __uint_as_float((unsigned)h << 16);
}

// ============ prep: out[n][k] = split_hi/lo(W[k][n]); K==256, grid=N ============
__global__ __launch_bounds__(256) void split_w_kernel(
    const float* __restrict__ W, ushort* __restrict__ hi, ushort* __restrict__ lo, int N)
{
  const int n = blockIdx.x, k = threadIdx.x;
  const float v = W[(size_t)k * N + n];
  const ushort h = f32_to_bf16(v);
  const ushort l = f32_to_bf16(v - bf16_to_f32(h));
  hi[(size_t)n * 256 + k] = h;
  lo[(size_t)n * 256 + k] = l;
}

// ============ prep: edge-block W1 (96x64) + W2 (64x64) -> [col][k] split ============
__global__ __launch_bounds__(256) void split_edge_w_kernel(
    const float* __restrict__ W1all, const float* __restrict__ W2all,
    ushort* __restrict__ w1h, ushort* __restrict__ w1l,
    ushort* __restrict__ w2h, ushort* __restrict__ w2l)
{
  const int b = blockIdx.x;
  const float* W1 = W1all + b * 6144;
  const float* W2 = W2all + b * 4096;
  for (int i = threadIdx.x; i < 6144; i += 256) {
    const int col = i / 96, k = i % 96;
    const float v = W1[k * 64 + col];
    const ushort h = f32_to_bf16(v);
    w1h[b * 6144 + col * 96 + k] = h;
    w1l[b * 6144 + col * 96 + k] = f32_to_bf16(v - bf16_to_f32(h));
  }
  for (int i = threadIdx.x; i < 4096; i += 256) {
    const int col = i >> 6, k = i & 63;
    const float v = W2[k * 64 + col];
    const ushort h = f32_to_bf16(v);
    w2h[b * 4096 + col * 64 + k] = h;
    w2l[b * 4096 + col * 64 + k] = f32_to_bf16(v - bf16_to_f32(h));
  }
}

// ============ prep: score sW (3x128x128) -> [layer][col][k] split ============
__global__ __launch_bounds__(128) void split_score_w_kernel(
    const float* __restrict__ sW, ushort* __restrict__ hi, ushort* __restrict__ lo)
{
  const int layer = blockIdx.x >> 7, col = blockIdx.x & 127, k = threadIdx.x;
  const float v = sW[layer * 16384 + k * 128 + col];
  const ushort h = f32_to_bf16(v);
  hi[layer * 16384 + col * 128 + k] = h;
  lo[layer * 16384 + col * 128 + k] = f32_to_bf16(v - bf16_to_f32(h));
}

// ===== prep: post W1/W2 (4x64x64) + outW (4x64x128) + fc1W (4x128x32) splits =====
__global__ __launch_bounds__(256) void split_post_w_kernel(
    const float* __restrict__ poW1, const float* __restrict__ poW2,
    const float* __restrict__ outW, const float* __restrict__ fc1W,
    ushort* __restrict__ p1h, ushort* __restrict__ p1l,
    ushort* __restrict__ p2h, ushort* __restrict__ p2l,
    ushort* __restrict__ oh,  ushort* __restrict__ ol,
    ushort* __restrict__ fh,  ushort* __restrict__ fl)
{
  const int b = blockIdx.x;
  for (int i = threadIdx.x; i < 4096; i += 256) {   // 64x64 -> [col][k]
    const int col = i >> 6, k = i & 63;
    float v = poW1[b * 4096 + k * 64 + col];
    ushort h = f32_to_bf16(v);
    p1h[b * 4096 + col * 64 + k] = h;
    p1l[b * 4096 + col * 64 + k] = f32_to_bf16(v - bf16_to_f32(h));
    v = poW2[b * 4096 + k * 64 + col];
    h = f32_to_bf16(v);
    p2h[b * 4096 + col * 64 + k] = h;
    p2l[b * 4096 + col * 64 + k] = f32_to_bf16(v - bf16_to_f32(h));
  }
  for (int i = threadIdx.x; i < 8192; i += 256) {   // 64x128 -> [col][k=64]
    const int col = i >> 6, k = i & 63;
    const float v = outW[b * 8192 + k * 128 + col];
    const ushort h = f32_to_bf16(v);
    oh[b * 8192 + col * 64 + k] = h;
    ol[b * 8192 + col * 64 + k] = f32_to_bf16(v - bf16_to_f32(h));
  }
  for (int i = threadIdx.x; i < 4096; i += 256) {   // 128x32 -> [col][k=128]
    const int col = i >> 7, k = i & 127;
    const float v = fc1W[b * 4096 + k * 32 + col];
    const ushort h = f32_to_bf16(v);
    fh[b * 4096 + col * 128 + k] = h;
    fl[b * 4096 + col * 128 + k] = f32_to_bf16(v - bf16_to_f32(h));
  }
}

// ===================== pairwise MLP: 9 -> 256 -> 256 -> 32 (R13 exact) =====================
#define A_STRIDE 264

__global__ __launch_bounds__(1024, 4) void pair_mlp_kernel(
    const float* __restrict__ raw,
    const float* __restrict__ W1, const float* __restrict__ b1,
    const ushort* __restrict__ w2h, const ushort* __restrict__ w2l,
    const float* __restrict__ b2,
    const ushort* __restrict__ w3h, const ushort* __restrict__ w3l,
    const float* __restrict__ b3,
    ushort* __restrict__ pair_h, ushort* __restrict__ pair_l)
{
  __shared__ __align__(16) ushort ah[64 * A_STRIDE];
  __shared__ __align__(16) ushort al[64 * A_STRIDE];
  __shared__ __align__(16) ushort w3sh[32 * A_STRIDE];
  __shared__ __align__(16) ushort w3sl[32 * A_STRIDE];
  __shared__ __align__(16) float rawt[64 * 12];

  const int t = threadIdx.x;
  const int lane = t & 63, wv = t >> 6;
  const int ln = lane & 15, kg = lane >> 4;

  for (int i = t; i < 32 * 64; i += 1024) {
    const int row = (i * 4) >> 8, col = (i * 4) & 255;
    *(ushort4*)&w3sh[row * A_STRIDE + col] = *(const ushort4*)&w3h[row * 256 + col];
    *(ushort4*)&w3sl[row * A_STRIDE + col] = *(const ushort4*)&w3l[row * 256 + col];
  }

  bf16x8 b2hreg[8], b2lreg[8];
  #pragma unroll
  for (int ks = 0; ks < 8; ++ks) {
    const size_t bo = (size_t)(wv * 16 + ln) * 256 + ks * 32 + kg * 8;
    b2hreg[ks] = *(const bf16x8*)&w2h[bo];
    b2lreg[ks] = *(const bf16x8*)&w2l[bo];
  }
  const float bias2 = b2[wv * 16 + ln];
  const int mt3 = (wv >> 1) & 3, nt3 = wv & 1;
  const float b3v = b3[nt3 * 16 + ln];
  __syncthreads();

  for (int grp = blockIdx.x; grp < E_EDGES / 64; grp += gridDim.x) {
    const long long e0 = (long long)grp * 64;

    if (t < 64 * 9) rawt[(t / 9) * 12 + (t % 9)] = raw[e0 * 9 + t];
    __syncthreads();

    {
      const int col = t & 255, r0 = (t >> 8) * 16;
      const float bv = b1[col];
      float wk[9];
      #pragma unroll
      for (int k = 0; k < 9; ++k) wk[k] = W1[k * 256 + col];
      #pragma unroll
      for (int r = 0; r < 16; ++r) {
        const int row = r0 + r;
        const float4 ra = *(const float4*)&rawt[row * 12];
        const float4 rb = *(const float4*)&rawt[row * 12 + 4];
        const float rc = rawt[row * 12 + 8];
        float s = bv;
        s = fmaf(ra.x, wk[0], s); s = fmaf(ra.y, wk[1], s);
        s = fmaf(ra.z, wk[2], s); s = fmaf(ra.w, wk[3], s);
        s = fmaf(rb.x, wk[4], s); s = fmaf(rb.y, wk[5], s);
        s = fmaf(rb.z, wk[6], s); s = fmaf(rb.w, wk[7], s);
        s = fmaf(rc, wk[8], s);
        const float v = fmaxf(s, 0.f);
        const ushort h = f32_to_bf16(v);
        ah[row * A_STRIDE + col] = h;
        al[row * A_STRIDE + col] = f32_to_bf16(v - bf16_to_f32(h));
      }
    }
    __syncthreads();

    f32x4 acc[4];
    #pragma unroll
    for (int mt = 0; mt < 4; ++mt) {
      acc[mt][0] = 0.f; acc[mt][1] = 0.f; acc[mt][2] = 0.f; acc[mt][3] = 0.f;
    }
    #pragma unroll
    for (int ks = 0; ks < 8; ++ks) {
      const int ka = ks * 32 + kg * 8;
      #pragma unroll
      for (int mt = 0; mt < 4; ++mt) {
        const bf16x8 ahf = *(const bf16x8*)&ah[(mt * 16 + ln) * A_STRIDE + ka];
        const bf16x8 alf = *(const bf16x8*)&al[(mt * 16 + ln) * A_STRIDE + ka];
        acc[mt] = __builtin_amdgcn_mfma_f32_16x16x32_bf16(ahf, b2hreg[ks], acc[mt], 0, 0, 0);
        acc[mt] = __builtin_amdgcn_mfma_f32_16x16x32_bf16(alf, b2hreg[ks], acc[mt], 0, 0, 0);
        acc[mt] = __builtin_amdgcn_mfma_f32_16x16x32_bf16(ahf, b2lreg[ks], acc[mt], 0, 0, 0);
      }
    }
    __syncthreads();

    {
      const int colg = wv * 16 + ln;
      #pragma unroll
      for (int mt = 0; mt < 4; ++mt)
        #pragma unroll
        for (int r = 0; r < 4; ++r) {
          const int rowe = mt * 16 + kg * 4 + r;
          const float v = fmaxf(acc[mt][r] + bias2, 0.f);
          const ushort h = f32_to_bf16(v);
          ah[rowe * A_STRIDE + colg] = h;
          al[rowe * A_STRIDE + colg] = f32_to_bf16(v - bf16_to_f32(h));
        }
    }
    __syncthreads();

    if (wv < 8) {
      f32x4 acc3;
      acc3[0] = 0.f; acc3[1] = 0.f; acc3[2] = 0.f; acc3[3] = 0.f;
      #pragma unroll
      for (int ks = 0; ks < 8; ++ks) {
        const int ka = ks * 32 + kg * 8;
        const bf16x8 a_h = *(const bf16x8*)&ah[(mt3 * 16 + ln) * A_STRIDE + ka];
        const bf16x8 a_l = *(const bf16x8*)&al[(mt3 * 16 + ln) * A_STRIDE + ka];
        const bf16x8 b_h = *(const bf16x8*)&w3sh[(nt3 * 16 + ln) * A_STRIDE + ka];
        const bf16x8 b_l = *(const bf16x8*)&w3sl[(nt3 * 16 + ln) * A_STRIDE + ka];
        acc3 = __builtin_amdgcn_mfma_f32_16x16x32_bf16(a_h, b_h, acc3, 0, 0, 0);
        acc3 = __builtin_amdgcn_mfma_f32_16x16x32_bf16(a_l, b_h, acc3, 0, 0, 0);
        acc3 = __builtin_amdgcn_mfma_f32_16x16x32_bf16(a_h, b_l, acc3, 0, 0, 0);
      }
      const int col3 = nt3 * 16 + ln;
      #pragma unroll
      for (int r = 0; r < 4; ++r) {
        const int rowe = mt3 * 16 + kg * 4 + r;
        const float v = fmaxf(acc3[r] + b3v, 0.f);
        const ushort h = f32_to_bf16(v);
        const size_t idx = (size_t)(e0 + rowe) * 32 + col3;
        pair_h[idx] = h;
        pair_l[idx] = f32_to_bf16(v - bf16_to_f32(h));
      }
    }
    __syncthreads();
  }
}

// ========== fc1 (b=0 only): f = relu(x @ fc1_W + b); emits f32 + split ==========
__global__ __launch_bounds__(256) void fc1_kernel(
    const float* __restrict__ x, const float* __restrict__ W,
    const float* __restrict__ b, float* __restrict__ f,
    ushort* __restrict__ f_h, ushort* __restrict__ f_l)
{
  __shared__ float Wl[128 * 32];
  const int t = threadIdx.x;
  #pragma unroll
  for (int j = 0; j < 4; ++j) {
    const int off = t * 4 + j * 1024;
    *(float4*)&Wl[off] = *(const float4*)&W[off];
  }
  __syncthreads();
  const int c = t & 31, rr = t >> 5;
  const long long r = (long long)blockIdx.x * 8 + rr;
  const float* xr = x + r * 128;
  float acc = b[c];
  #pragma unroll 8
  for (int k = 0; k < 128; k += 4) {
    const float4 a = *(const float4*)&xr[k];
    acc = fmaf(a.x, Wl[(k + 0) * 32 + c], acc);
    acc = fmaf(a.y, Wl[(k + 1) * 32 + c], acc);
    acc = fmaf(a.z, Wl[(k + 2) * 32 + c], acc);
    acc = fmaf(a.w, Wl[(k + 3) * 32 + c], acc);
  }
  const float v = fmaxf(acc, 0.f);
  f[r * 32 + c] = v;
  const ushort h = f32_to_bf16(v);
  f_h[r * 32 + c] = h;
  f_l[r * 32 + c] = f32_to_bf16(v - bf16_to_f32(h));
}

// ====== edge MLP (96->64->64) + segment-max, split-bf16 MFMA, persistent ======
#define W1S 104
#define W2S 72
#define CTS 36

__global__ __launch_bounds__(512, 2) void edge_kernel(
    const ushort* __restrict__ pair_h, const ushort* __restrict__ pair_l,
    const float* __restrict__ f,
    const ushort* __restrict__ f_h, const ushort* __restrict__ f_l,
    const int* __restrict__ nIdxs,
    const float* __restrict__ W1g, const float* __restrict__ bb1,
    const ushort* __restrict__ gw1h, const ushort* __restrict__ gw1l,
    const ushort* __restrict__ gw2h, const ushort* __restrict__ gw2l,
    const float* __restrict__ bb2,
    float* __restrict__ m)
{
  __shared__ __align__(16) ushort W1hS[64 * W1S], W1lS[64 * W1S];
  __shared__ __align__(16) ushort W2hS[64 * W2S], W2lS[64 * W2S];
  __shared__ __align__(16) float  W1cT[64 * CTS];
  __shared__ __align__(16) ushort h1h[8][32 * W2S], h1l[8][32 * W2S];

  const int t = threadIdx.x;
  const int lane = t & 63, wv = t >> 6;
  const int ln = lane & 15, kg = lane >> 4;

  for (int i = t; i < 1536; i += 512) {
    const int idx = i * 4, row = idx / 96, k = idx % 96;
    *(ushort4*)&W1hS[row * W1S + k] = *(const ushort4*)&gw1h[idx];
    *(ushort4*)&W1lS[row * W1S + k] = *(const ushort4*)&gw1l[idx];
  }
  for (int i = t; i < 1024; i += 512) {
    const int idx = i * 4, row = idx >> 6, k = idx & 63;
    *(ushort4*)&W2hS[row * W2S + k] = *(const ushort4*)&gw2h[idx];
    *(ushort4*)&W2lS[row * W2S + k] = *(const ushort4*)&gw2l[idx];
  }
  for (int i = t; i < 2048; i += 512) {
    const int col = i >> 5, j = i & 31;
    W1cT[col * CTS + j] = W1g[(32 + j) * 64 + col];
  }
  __syncthreads();

  for (int dg = blockIdx.x; dg < N_DETS / 8; dg += gridDim.x) {
    const int d = dg * 8 + wv;
    const long long e0 = (long long)d * 32;

    float cfs[4];
    {
      const float4 fv0 = *(const float4*)&f[(size_t)d * 32 + kg * 8];
      const float4 fv1 = *(const float4*)&f[(size_t)d * 32 + kg * 8 + 4];
      #pragma unroll
      for (int nt = 0; nt < 4; ++nt) {
        const int col = nt * 16 + ln;
        const float4 w0 = *(const float4*)&W1cT[col * CTS + kg * 8];
        const float4 w1 = *(const float4*)&W1cT[col * CTS + kg * 8 + 4];
        float s = fv0.x * w0.x + fv0.y * w0.y + fv0.z * w0.z + fv0.w * w0.w
                + fv1.x * w1.x + fv1.y * w1.y + fv1.z * w1.z + fv1.w * w1.w;
        s += __shfl_xor(s, 16);
        s += __shfl_xor(s, 32);
        cfs[nt] = s + bb1[col];
      }
    }

    f32x4 acc1[4][2];
    #pragma unroll
    for (int nt = 0; nt < 4; ++nt)
      #pragma unroll
      for (int mt = 0; mt < 2; ++mt) {
        acc1[nt][mt][0] = 0.f; acc1[nt][mt][1] = 0.f;
        acc1[nt][mt][2] = 0.f; acc1[nt][mt][3] = 0.f;
      }
    bf16x8 ph[2], pl_[2], nh[2], nl_[2];
    #pragma unroll
    for (int mt = 0; mt < 2; ++mt) {
      const long long row = e0 + mt * 16 + ln;
      ph[mt]  = *(const bf16x8*)&pair_h[row * 32 + kg * 8];
      pl_[mt] = *(const bf16x8*)&pair_l[row * 32 + kg * 8];
      const int n = nIdxs[row];
      bf16x8 vh = *(const bf16x8*)&f_h[(size_t)n * 32 + kg * 8];
      bf16x8 vl = *(const bf16x8*)&f_l[(size_t)n * 32 + kg * 8];
      if (n == d) { vh = (bf16x8){0,0,0,0,0,0,0,0}; vl = (bf16x8){0,0,0,0,0,0,0,0}; }
      nh[mt] = vh; nl_[mt] = vl;
    }
    #pragma unroll
    for (int nt = 0; nt < 4; ++nt) {
      const int bro = (nt * 16 + ln) * W1S;
      const bf16x8 b0h = *(const bf16x8*)&W1hS[bro + kg * 8];
      const bf16x8 b0l = *(const bf16x8*)&W1lS[bro + kg * 8];
      const bf16x8 b1h = *(const bf16x8*)&W1hS[bro + 64 + kg * 8];
      const bf16x8 b1l = *(const bf16x8*)&W1lS[bro + 64 + kg * 8];
      #pragma unroll
      for (int mt = 0; mt < 2; ++mt) {
        acc1[nt][mt] = __builtin_amdgcn_mfma_f32_16x16x32_bf16(ph[mt], b0h, acc1[nt][mt], 0, 0, 0);
        acc1[nt][mt] = __builtin_amdgcn_mfma_f32_16x16x32_bf16(pl_[mt], b0h, acc1[nt][mt], 0, 0, 0);
        acc1[nt][mt] = __builtin_amdgcn_mfma_f32_16x16x32_bf16(ph[mt], b0l, acc1[nt][mt], 0, 0, 0);
        acc1[nt][mt] = __builtin_amdgcn_mfma_f32_16x16x32_bf16(nh[mt], b1h, acc1[nt][mt], 0, 0, 0);
        acc1[nt][mt] = __builtin_amdgcn_mfma_f32_16x16x32_bf16(nl_[mt], b1h, acc1[nt][mt], 0, 0, 0);
        acc1[nt][mt] = __builtin_amdgcn_mfma_f32_16x16x32_bf16(nh[mt], b1l, acc1[nt][mt], 0, 0, 0);
      }
    }

    #pragma unroll
    for (int nt = 0; nt < 4; ++nt) {
      const int col = nt * 16 + ln;
      #pragma unroll
      for (int mt = 0; mt < 2; ++mt)
        #pragma unroll
        for (int r = 0; r < 4; ++r) {
          const int row = mt * 16 + kg * 4 + r;
          const float v = fmaxf(acc1[nt][mt][r] + cfs[nt], 0.f);
          const ushort h = f32_to_bf16(v);
          h1h[wv][row * W2S + col] = h;
          h1l[wv][row * W2S + col] = f32_to_bf16(v - bf16_to_f32(h));
        }
    }

    f32x4 acc2[4][2];
    #pragma unroll
    for (int mt = 0; mt < 4; ++mt)
      #pragma unroll
      for (int nt = 0; nt < 2; ++nt) {
        acc2[mt][nt][0] = 0.f; acc2[mt][nt][1] = 0.f;
        acc2[mt][nt][2] = 0.f; acc2[mt][nt][3] = 0.f;
      }
    #pragma unroll
    for (int ks = 0; ks < 2; ++ks) {
      const int ka = ks * 32 + kg * 8;
      bf16x8 bh[2], bl[2];
      #pragma unroll
      for (int nt = 0; nt < 2; ++nt) {
        bh[nt] = *(const bf16x8*)&h1h[wv][(nt * 16 + ln) * W2S + ka];
        bl[nt] = *(const bf16x8*)&h1l[wv][(nt * 16 + ln) * W2S + ka];
      }
      #pragma unroll
      for (int mt = 0; mt < 4; ++mt) {
        const bf16x8 a_h = *(const bf16x8*)&W2hS[(mt * 16 + ln) * W2S + ka];
        const bf16x8 a_l = *(const bf16x8*)&W2lS[(mt * 16 + ln) * W2S + ka];
        #pragma unroll
        for (int nt = 0; nt < 2; ++nt) {
          acc2[mt][nt] = __builtin_amdgcn_mfma_f32_16x16x32_bf16(a_h, bh[nt], acc2[mt][nt], 0, 0, 0);
          acc2[mt][nt] = __builtin_amdgcn_mfma_f32_16x16x32_bf16(a_h, bl[nt], acc2[mt][nt], 0, 0, 0);
          acc2[mt][nt] = __builtin_amdgcn_mfma_f32_16x16x32_bf16(a_l, bh[nt], acc2[mt][nt], 0, 0, 0);
        }
      }
    }

    #pragma unroll
    for (int mt = 0; mt < 4; ++mt)
      #pragma unroll
      for (int r = 0; r < 4; ++r) {
        float mx = fmaxf(acc2[mt][0][r], acc2[mt][1][r]);
        mx = fmaxf(mx, __shfl_xor(mx, 1));
        mx = fmaxf(mx, __shfl_xor(mx, 2));
        mx = fmaxf(mx, __shfl_xor(mx, 4));
        mx = fmaxf(mx, __shfl_xor(mx, 8));
        if (ln == mt * 4 + r) {
          const int outcol = mt * 16 + kg * 4 + r;
          m[(size_t)d * 64 + outcol] = fmaxf(mx + bb2[outcol], 0.f);
        }
      }
  }
}

// === fused post+fc1: y=relu(x + MLP(m)@Wo+bo); f_next=relu(y@fc1W+b) [MFMA] ===
#define PS 72    // stride for 64-wide split tiles
#define PXS 136  // stride for 128-wide split tiles

__global__ __launch_bounds__(512) void postfc1_kernel(
    const float* __restrict__ m, const float* __restrict__ x,
    const ushort* __restrict__ p1h, const ushort* __restrict__ p1l,
    const float* __restrict__ pob1,
    const ushort* __restrict__ p2h, const ushort* __restrict__ p2l,
    const float* __restrict__ pob2,
    const ushort* __restrict__ oh, const ushort* __restrict__ ol,
    const float* __restrict__ outb,
    const ushort* __restrict__ fch, const ushort* __restrict__ fcl,
    const float* __restrict__ fcb, int do_fc1,
    float* __restrict__ y,
    float* __restrict__ f, ushort* __restrict__ f_h, ushort* __restrict__ f_l)
{
  __shared__ __align__(16) ushort mh[32 * PS], ml[32 * PS];   // m (then h2)
  __shared__ __align__(16) ushort hh[32 * PS], hl[32 * PS];   // h1
  __shared__ __align__(16) ushort yh[32 * PXS], yl[32 * PXS]; // y split
  const int t = threadIdx.x;
  const int lane = t & 63, wv = t >> 6;
  const int ln = lane & 15, kg = lane >> 4;
  const long long r0 = (long long)blockIdx.x * 32;

  // stage m split
  for (int i = t; i < 32 * 16; i += 512) {
    const int row = i >> 4, cq = (i & 15) * 4;
    const float4 v4 = *(const float4*)&m[(r0 + row) * 64 + cq];
    const float vv[4] = {v4.x, v4.y, v4.z, v4.w};
    #pragma unroll
    for (int j = 0; j < 4; ++j) {
      const ushort h = f32_to_bf16(vv[j]);
      mh[row * PS + cq + j] = h;
      ml[row * PS + cq + j] = f32_to_bf16(vv[j] - bf16_to_f32(h));
    }
  }
  __syncthreads();

  // layer1: 32x64, wave -> (mt=wv>>2, nt=wv&3)
  {
    const int mt = wv >> 2, nt = wv & 3, col = nt * 16 + ln;
    const ushort* bh = p1h + (size_t)col * 64;
    const ushort* bl = p1l + (size_t)col * 64;
    f32x4 acc; acc[0] = 0.f; acc[1] = 0.f; acc[2] = 0.f; acc[3] = 0.f;
    #pragma unroll
    for (int ks = 0; ks < 2; ++ks) {
      const int ka = ks * 32 + kg * 8;
      const bf16x8 a_h = *(const bf16x8*)&mh[(mt * 16 + ln) * PS + ka];
      const bf16x8 a_l = *(const bf16x8*)&ml[(mt * 16 + ln) * PS + ka];
      const bf16x8 b_h = *(const bf16x8*)&bh[ka];
      const bf16x8 b_l = *(const bf16x8*)&bl[ka];
      acc = __builtin_amdgcn_mfma_f32_16x16x32_bf16(a_h, b_h, acc, 0, 0, 0);
      acc = __builtin_amdgcn_mfma_f32_16x16x32_bf16(a_l, b_h, acc, 0, 0, 0);
      acc = __builtin_amdgcn_mfma_f32_16x16x32_bf16(a_h, b_l, acc, 0, 0, 0);
    }
    const float bias = pob1[col];
    #pragma unroll
    for (int r = 0; r < 4; ++r) {
      const int row = mt * 16 + kg * 4 + r;
      const float v = fmaxf(acc[r] + bias, 0.f);
      const ushort h = f32_to_bf16(v);
      hh[row * PS + col] = h;
      hl[row * PS + col] = f32_to_bf16(v - bf16_to_f32(h));
    }
  }
  __syncthreads();

  // layer2: 32x64, reads h1, writes h2 into mh/ml
  {
    const int mt = wv >> 2, nt = wv & 3, col = nt * 16 + ln;
    const ushort* bh = p2h + (size_t)col * 64;
    const ushort* bl = p2l + (size_t)col * 64;
    f32x4 acc; acc[0] = 0.f; acc[1] = 0.f; acc[2] = 0.f; acc[3] = 0.f;
    #pragma unroll
    for (int ks = 0; ks < 2; ++ks) {
      const int ka = ks * 32 + kg * 8;
      const bf16x8 a_h = *(const bf16x8*)&hh[(mt * 16 + ln) * PS + ka];
      const bf16x8 a_l = *(const bf16x8*)&hl[(mt * 16 + ln) * PS + ka];
      const bf16x8 b_h = *(const bf16x8*)&bh[ka];
      const bf16x8 b_l = *(const bf16x8*)&bl[ka];
      acc = __builtin_amdgcn_mfma_f32_16x16x32_bf16(a_h, b_h, acc, 0, 0, 0);
      acc = __builtin_amdgcn_mfma_f32_16x16x32_bf16(a_l, b_h, acc, 0, 0, 0);
      acc = __builtin_amdgcn_mfma_f32_16x16x32_bf16(a_h, b_l, acc, 0, 0, 0);
    }
    const float bias = pob2[col];
    __syncthreads();   // all reads of mh (layer1 A) done before overwrite
    #pragma unroll
    for (int r = 0; r < 4; ++r) {
      const int row = mt * 16 + kg * 4 + r;
      const float v = fmaxf(acc[r] + bias, 0.f);
      const ushort h = f32_to_bf16(v);
      mh[row * PS + col] = h;
      ml[row * PS + col] = f32_to_bf16(v - bf16_to_f32(h));
    }
  }
  __syncthreads();

  // layer3: 32x128 + residual; wave owns cols wv*16..+16, both M-tiles
  {
    const int col = wv * 16 + ln;
    const ushort* bh = oh + (size_t)col * 64;
    const ushort* bl = ol + (size_t)col * 64;
    f32x4 acc[2];
    #pragma unroll
    for (int mt = 0; mt < 2; ++mt) {
      acc[mt][0] = 0.f; acc[mt][1] = 0.f; acc[mt][2] = 0.f; acc[mt][3] = 0.f;
    }
    #pragma unroll
    for (int ks = 0; ks < 2; ++ks) {
      const int ka = ks * 32 + kg * 8;
      const bf16x8 b_h = *(const bf16x8*)&bh[ka];
      const bf16x8 b_l = *(const bf16x8*)&bl[ka];
      #pragma unroll
      for (int mt = 0; mt < 2; ++mt) {
        const bf16x8 a_h = *(const bf16x8*)&mh[(mt * 16 + ln) * PS + ka];
        const bf16x8 a_l = *(const bf16x8*)&ml[(mt * 16 + ln) * PS + ka];
        acc[mt] = __builtin_amdgcn_mfma_f32_16x16x32_bf16(a_h, b_h, acc[mt], 0, 0, 0);
        acc[mt] = __builtin_amdgcn_mfma_f32_16x16x32_bf16(a_l, b_h, acc[mt], 0, 0, 0);
        acc[mt] = __builtin_amdgcn_mfma_f32_16x16x32_bf16(a_h, b_l, acc[mt], 0, 0, 0);
      }
    }
    const float bias = outb[col];
    #pragma unroll
    for (int mt = 0; mt < 2; ++mt)
      #pragma unroll
      for (int r = 0; r < 4; ++r) {
        const int row = mt * 16 + kg * 4 + r;
        const size_t idx = (size_t)(r0 + row) * 128 + col;
        const float v = fmaxf(x[idx] + acc[mt][r] + bias, 0.f);
        y[idx] = v;
        const ushort h = f32_to_bf16(v);
        yh[row * PXS + col] = h;
        yl[row * PXS + col] = f32_to_bf16(v - bf16_to_f32(h));
      }
  }
  __syncthreads();

  // fused fc1 for next block: 32x32, K=128; waves 0-3
  if (do_fc1 && wv < 4) {
    const int mt = wv >> 1, nt = wv & 1, col = nt * 16 + ln;
    const ushort* bh = fch + (size_t)col * 128;
    const ushort* bl = fcl + (size_t)col * 128;
    f32x4 acc; acc[0] = 0.f; acc[1] = 0.f; acc[2] = 0.f; acc[3] = 0.f;
    #pragma unroll
    for (int ks = 0; ks < 4; ++ks) {
      const int ka = ks * 32 + kg * 8;
      const bf16x8 a_h = *(const bf16x8*)&yh[(mt * 16 + ln) * PXS + ka];
      const bf16x8 a_l = *(const bf16x8*)&yl[(mt * 16 + ln) * PXS + ka];
      const bf16x8 b_h = *(const bf16x8*)&bh[ka];
      const bf16x8 b_l = *(const bf16x8*)&bl[ka];
      acc = __builtin_amdgcn_mfma_f32_16x16x32_bf16(a_h, b_h, acc, 0, 0, 0);
      acc = __builtin_amdgcn_mfma_f32_16x16x32_bf16(a_l, b_h, acc, 0, 0, 0);
      acc = __builtin_amdgcn_mfma_f32_16x16x32_bf16(a_h, b_l, acc, 0, 0, 0);
    }
    const float bias = fcb[col];
    #pragma unroll
    for (int r = 0; r < 4; ++r) {
      const int row = mt * 16 + kg * 4 + r;
      const float v = fmaxf(acc[r] + bias, 0.f);
      const size_t idx = (size_t)(r0 + row) * 32 + col;
      f[idx] = v;
      const ushort h = f32_to_bf16(v);
      f_h[idx] = h;
      f_l[idx] = f32_to_bf16(v - bf16_to_f32(h));
    }
  }
}

// ====== score head: 3x (128->128 relu) + dot, split-bf16 MFMA, 32 rows/block ======
#define XS 136

__global__ __launch_bounds__(512) void score_head_kernel(
    const float* __restrict__ x,
    const ushort* __restrict__ swh, const ushort* __restrict__ swl,
    const float* __restrict__ sb,
    const float* __restrict__ pW, const float* __restrict__ pb,
    float* __restrict__ out)
{
  __shared__ __align__(16) ushort xh[2][32 * XS], xl[2][32 * XS];
  __shared__ __align__(16) float hsf[32 * XS];
  __shared__ float pWs[128];
  const int t = threadIdx.x;
  const int lane = t & 63, wv = t >> 6;
  const int ln = lane & 15, kg = lane >> 4;
  const long long r0 = (long long)blockIdx.x * 32;

  if (t < 128) pWs[t] = pW[t];
  for (int i = t; i < 32 * 32; i += 512) {
    const int row = i >> 5, cq = (i & 31) * 4;
    const float4 v4 = *(const float4*)&x[(r0 + row) * 128 + cq];
    const float vv[4] = {v4.x, v4.y, v4.z, v4.w};
    #pragma unroll
    for (int j = 0; j < 4; ++j) {
      const ushort h = f32_to_bf16(vv[j]);
      xh[0][row * XS + cq + j] = h;
      xl[0][row * XS + cq + j] = f32_to_bf16(vv[j] - bf16_to_f32(h));
    }
  }
  __syncthreads();

  const int colg = wv * 16 + ln;
  int cur = 0;
  #pragma unroll 1
  for (int layer = 0; layer < 3; ++layer) {
    const ushort* wh = swh + (size_t)layer * 16384 + (size_t)colg * 128;
    const ushort* wl = swl + (size_t)layer * 16384 + (size_t)colg * 128;
    f32x4 acc[2];
    #pragma unroll
    for (int mt = 0; mt < 2; ++mt) {
      acc[mt][0] = 0.f; acc[mt][1] = 0.f; acc[mt][2] = 0.f; acc[mt][3] = 0.f;
    }
    #pragma unroll
    for (int ks = 0; ks < 4; ++ks) {
      const int ka = ks * 32 + kg * 8;
      const bf16x8 b_h = *(const bf16x8*)&wh[ka];
      const bf16x8 b_l = *(const bf16x8*)&wl[ka];
      #pragma unroll
      for (int mt = 0; mt < 2; ++mt) {
        const bf16x8 a_h = *(const bf16x8*)&xh[cur][(mt * 16 + ln) * XS + ka];
        const bf16x8 a_l = *(const bf16x8*)&xl[cur][(mt * 16 + ln) * XS + ka];
        acc[mt] = __builtin_amdgcn_mfma_f32_16x16x32_bf16(a_h, b_h, acc[mt], 0, 0, 0);
        acc[mt] = __builtin_amdgcn_mfma_f32_16x16x32_bf16(a_l, b_h, acc[mt], 0, 0, 0);
        acc[mt] = __builtin_amdgcn_mfma_f32_16x16x32_bf16(a_h, b_l, acc[mt], 0, 0, 0);
      }
    }
    const float bias = sb[layer * 128 + colg];
    __syncthreads();
    if (layer < 2) {
      #pragma unroll
      for (int mt = 0; mt < 2; ++mt)
        #pragma unroll
        for (int r = 0; r < 4; ++r) {
          const int row = mt * 16 + kg * 4 + r;
          const float v = fmaxf(acc[mt][r] + bias, 0.f);
          const ushort h = f32_to_bf16(v);
          xh[cur ^ 1][row * XS + colg] = h;
          xl[cur ^ 1][row * XS + colg] = f32_to_bf16(v - bf16_to_f32(h));
        }
      cur ^= 1;
    } else {
      #pragma unroll
      for (int mt = 0; mt < 2; ++mt)
        #pragma unroll
        for (int r = 0; r < 4; ++r) {
          const int row = mt * 16 + kg * 4 + r;
          hsf[row * XS + colg] = fmaxf(acc[mt][r] + bias, 0.f);
        }
    }
    __syncthreads();
  }

  {
    const int row = t >> 4, l16 = t & 15;
    const float4 a0 = *(const float4*)&hsf[row * XS + l16 * 8];
    const float4 a1 = *(const float4*)&hsf[row * XS + l16 * 8 + 4];
    const float4 w0 = *(const float4*)&pWs[l16 * 8];
    const float4 w1 = *(const float4*)&pWs[l16 * 8 + 4];
    float s = a0.x * w0.x + a0.y * w0.y + a0.z * w0.z + a0.w * w0.w
            + a1.x * w1.x + a1.y * w1.y + a1.z * w1.z + a1.w * w1.w;
    s += __shfl_xor(s, 1);
    s += __shfl_xor(s, 2);
    s += __shfl_xor(s, 4);
    s += __shfl_xor(s, 8);
    if (l16 == 0) out[r0 + row] = s + pb[0];
  }
}

extern "C" void kernel_launch(void* const* d_in, const int* in_sizes, int n_in,
                              void* d_out, int out_size, void* d_ws, size_t ws_size,
                              hipStream_t stream)
{
  const float* detF    = (const float*)d_in[0];
  const float* pairRaw = (const float*)d_in[1];
  const int*   cIdx    = (const int*)d_in[2];
  const int*   nIdx    = (const int*)d_in[3];
  const float* gW1 = (const float*)d_in[4];   const float* gb1 = (const float*)d_in[5];
  const float* gW2 = (const float*)d_in[6];   const float* gb2 = (const float*)d_in[7];
  const float* gW3 = (const float*)d_in[8];   const float* gb3 = (const float*)d_in[9];
  const float* fc1W = (const float*)d_in[10]; const float* fc1b = (const float*)d_in[11];
  const float* pwW1 = (const float*)d_in[12]; const float* pwb1 = (const float*)d_in[13];
  const float* pwW2 = (const float*)d_in[14]; const float* pwb2 = (const float*)d_in[15];
  const float* poW1 = (const float*)d_in[16]; const float* pob1 = (const float*)d_in[17];
  const float* poW2 = (const float*)d_in[18]; const float* pob2 = (const float*)d_in[19];
  const float* outW = (const float*)d_in[20]; const float* outb = (const float*)d_in[21];
  const float* sW = (const float*)d_in[22];   const float* sb = (const float*)d_in[23];
  const float* predW = (const float*)d_in[24]; const float* predb = (const float*)d_in[25];
  float* out = (float*)d_out;
  (void)cIdx;   // cIdxs == repeat(arange(N), DEG) per setup; d = e >> 5

  ushort* w2h  = (ushort*)d_ws;
  ushort* w2l  = w2h + 65536;
  ushort* w3h  = w2l + 65536;
  ushort* w3l  = w3h + 8192;
  ushort* w1eh = w3l + 8192;
  ushort* w1el = w1eh + 24576;
  ushort* w2eh = w1el + 24576;
  ushort* w2el = w2eh + 16384;
  ushort* swh  = w2el + 16384;                 // 3*16384
  ushort* swl  = swh + 49152;
  ushort* p1h  = swl + 49152;                  // 4*4096
  ushort* p1l  = p1h + 16384;
  ushort* p2h  = p1l + 16384;
  ushort* p2l  = p2h + 16384;
  ushort* ohh  = p2l + 16384;                  // 4*8192
  ushort* ohl  = ohh + 32768;
  ushort* fth  = ohl + 32768;                  // 4*4096
  ushort* ftl  = fth + 16384;
  ushort* pair_h = ftl + 16384;
  ushort* pair_l = pair_h + (size_t)E_EDGES * 32;
  ushort* f_h    = pair_l + (size_t)E_EDGES * 32;
  ushort* f_l    = f_h + (size_t)N_DETS * 32;
  float* f  = (float*)(f_l + (size_t)N_DETS * 32);
  float* m  = f  + (size_t)N_DETS * 32;
  float* xa = m  + (size_t)N_DETS * 64;
  float* xb = xa + (size_t)N_DETS * 128;

  hipMemcpyAsync(xa, detF, (size_t)N_DETS * 128 * sizeof(float),
                 hipMemcpyDeviceToDevice, stream);

  split_w_kernel<<<256, 256, 0, stream>>>(gW2, w2h, w2l, 256);
  split_w_kernel<<<32, 256, 0, stream>>>(gW3, w3h, w3l, 32);
  split_edge_w_kernel<<<4, 256, 0, stream>>>(pwW1, pwW2, w1eh, w1el, w2eh, w2el);
  split_score_w_kernel<<<384, 128, 0, stream>>>(sW, swh, swl);
  split_post_w_kernel<<<4, 256, 0, stream>>>(poW1, poW2, outW, fc1W,
      p1h, p1l, p2h, p2l, ohh, ohl, fth, ftl);

  pair_mlp_kernel<<<256, 1024, 0, stream>>>(pairRaw, gW1, gb1,
      w2h, w2l, gb2, w3h, w3l, gb3, pair_h, pair_l);

  // b=0 fc1 standalone
  fc1_kernel<<<N_DETS / 8, 256, 0, stream>>>(xa, fc1W, fc1b, f, f_h, f_l);

  float* xin = xa;
  float* xout = xb;
  for (int b = 0; b < 4; ++b) {
    edge_kernel<<<EDGE_GRID, 512, 0, stream>>>(pair_h, pair_l, f, f_h, f_l, nIdx,
        pwW1 + b * 6144, pwb1 + b * 64,
        w1eh + b * 6144, w1el + b * 6144, w2eh + b * 4096, w2el + b * 4096,
        pwb2 + b * 64, m);
    const int nb = (b + 1) & 3;
    postfc1_kernel<<<N_DETS / 32, 512, 0, stream>>>(m, xin,
        p1h + b * 4096, p1l + b * 4096, pob1 + b * 64,
        p2h + b * 4096, p2l + b * 4096, pob2 + b * 64,
        ohh + b * 8192, ohl + b * 8192, outb + b * 128,
        fth + nb * 4096, ftl + nb * 4096, fc1b + nb * 32, (b < 3) ? 1 : 0,
        xout, f, f_h, f_l);
    float* tmp = xout; xout = xin; xin = tmp;
  }
  score_head_kernel<<<N_DETS / 32, 512, 0, stream>>>(xin, swh, swl, sb,
      predW, predb, out);
}

// Round 22
// 672.220 us; speedup vs baseline: 1.5675x; 1.0089x over previous
//
#include <hip/hip_runtime.h>

// R22: fuse post12+postout+fc1 INTO the edge kernel (edge_post_kernel).
// Block owns 32 contiguous dets (4 iters x 8); m written straight to LDS in
// split form (numerics identical to R21's global-f32-then-split); post body
// (from postfc1) runs from LDS, temporaries alias the h1 region. f double-
// buffered to remove the kernel-boundary race. Saves 4 launches + m traffic.
#define N_DETS 16384
#define DEG 32
#define E_EDGES (N_DETS * DEG)   // 524288

typedef __attribute__((ext_vector_type(8))) short bf16x8;
typedef __attribute__((ext_vector_type(4))) float f32x4;

__device__ __forceinline__ ushort f32_to_bf16(float v) {
  unsigned u = __float_as_uint(v);
  u += 0x7FFFu + ((u >> 16) & 1u);    // round-to-nearest-even
  return (ushort)(u >> 16);
}
__device__ __forceinline__ float bf16_to_f32(ushort h) {
  return __uint_as_float((unsigned)h << 16);
}

// ============ prep: out[n][k] = split_hi/lo(W[k][n]); K==256, grid=N ============
__global__ __launch_bounds__(256) void split_w_kernel(
    const float* __restrict__ W, ushort* __restrict__ hi, ushort* __restrict__ lo, int N)
{
  const int n = blockIdx.x, k = threadIdx.x;
  const float v = W[(size_t)k * N + n];
  const ushort h = f32_to_bf16(v);
  const ushort l = f32_to_bf16(v - bf16_to_f32(h));
  hi[(size_t)n * 256 + k] = h;
  lo[(size_t)n * 256 + k] = l;
}

// ============ prep: edge-block W1 (96x64) + W2 (64x64) -> [col][k] split ============
__global__ __launch_bounds__(256) void split_edge_w_kernel(
    const float* __restrict__ W1all, const float* __restrict__ W2all,
    ushort* __restrict__ w1h, ushort* __restrict__ w1l,
    ushort* __restrict__ w2h, ushort* __restrict__ w2l)
{
  const int b = blockIdx.x;
  const float* W1 = W1all + b * 6144;
  const float* W2 = W2all + b * 4096;
  for (int i = threadIdx.x; i < 6144; i += 256) {
    const int col = i / 96, k = i % 96;
    const float v = W1[k * 64 + col];
    const ushort h = f32_to_bf16(v);
    w1h[b * 6144 + col * 96 + k] = h;
    w1l[b * 6144 + col * 96 + k] = f32_to_bf16(v - bf16_to_f32(h));
  }
  for (int i = threadIdx.x; i < 4096; i += 256) {
    const int col = i >> 6, k = i & 63;
    const float v = W2[k * 64 + col];
    const ushort h = f32_to_bf16(v);
    w2h[b * 4096 + col * 64 + k] = h;
    w2l[b * 4096 + col * 64 + k] = f32_to_bf16(v - bf16_to_f32(h));
  }
}

// ============ prep: score sW (3x128x128) -> [layer][col][k] split ============
__global__ __launch_bounds__(128) void split_score_w_kernel(
    const float* __restrict__ sW, ushort* __restrict__ hi, ushort* __restrict__ lo)
{
  const int layer = blockIdx.x >> 7, col = blockIdx.x & 127, k = threadIdx.x;
  const float v = sW[layer * 16384 + k * 128 + col];
  const ushort h = f32_to_bf16(v);
  hi[layer * 16384 + col * 128 + k] = h;
  lo[layer * 16384 + col * 128 + k] = f32_to_bf16(v - bf16_to_f32(h));
}

// ===== prep: post W1/W2 (4x64x64) + outW (4x64x128) + fc1W (4x128x32) splits =====
__global__ __launch_bounds__(256) void split_post_w_kernel(
    const float* __restrict__ poW1, const float* __restrict__ poW2,
    const float* __restrict__ outW, const float* __restrict__ fc1W,
    ushort* __restrict__ p1h, ushort* __restrict__ p1l,
    ushort* __restrict__ p2h, ushort* __restrict__ p2l,
    ushort* __restrict__ oh,  ushort* __restrict__ ol,
    ushort* __restrict__ fh,  ushort* __restrict__ fl)
{
  const int b = blockIdx.x;
  for (int i = threadIdx.x; i < 4096; i += 256) {   // 64x64 -> [col][k]
    const int col = i >> 6, k = i & 63;
    float v = poW1[b * 4096 + k * 64 + col];
    ushort h = f32_to_bf16(v);
    p1h[b * 4096 + col * 64 + k] = h;
    p1l[b * 4096 + col * 64 + k] = f32_to_bf16(v - bf16_to_f32(h));
    v = poW2[b * 4096 + k * 64 + col];
    h = f32_to_bf16(v);
    p2h[b * 4096 + col * 64 + k] = h;
    p2l[b * 4096 + col * 64 + k] = f32_to_bf16(v - bf16_to_f32(h));
  }
  for (int i = threadIdx.x; i < 8192; i += 256) {   // 64x128 -> [col][k=64]
    const int col = i >> 6, k = i & 63;
    const float v = outW[b * 8192 + k * 128 + col];
    const ushort h = f32_to_bf16(v);
    oh[b * 8192 + col * 64 + k] = h;
    ol[b * 8192 + col * 64 + k] = f32_to_bf16(v - bf16_to_f32(h));
  }
  for (int i = threadIdx.x; i < 4096; i += 256) {   // 128x32 -> [col][k=128]
    const int col = i >> 7, k = i & 127;
    const float v = fc1W[b * 4096 + k * 32 + col];
    const ushort h = f32_to_bf16(v);
    fh[b * 4096 + col * 128 + k] = h;
    fl[b * 4096 + col * 128 + k] = f32_to_bf16(v - bf16_to_f32(h));
  }
}

// ===================== pairwise MLP: 9 -> 256 -> 256 -> 32 (R13 exact) =====================
#define A_STRIDE 264

__global__ __launch_bounds__(1024, 4) void pair_mlp_kernel(
    const float* __restrict__ raw,
    const float* __restrict__ W1, const float* __restrict__ b1,
    const ushort* __restrict__ w2h, const ushort* __restrict__ w2l,
    const float* __restrict__ b2,
    const ushort* __restrict__ w3h, const ushort* __restrict__ w3l,
    const float* __restrict__ b3,
    ushort* __restrict__ pair_h, ushort* __restrict__ pair_l)
{
  __shared__ __align__(16) ushort ah[64 * A_STRIDE];
  __shared__ __align__(16) ushort al[64 * A_STRIDE];
  __shared__ __align__(16) ushort w3sh[32 * A_STRIDE];
  __shared__ __align__(16) ushort w3sl[32 * A_STRIDE];
  __shared__ __align__(16) float rawt[64 * 12];

  const int t = threadIdx.x;
  const int lane = t & 63, wv = t >> 6;
  const int ln = lane & 15, kg = lane >> 4;

  for (int i = t; i < 32 * 64; i += 1024) {
    const int row = (i * 4) >> 8, col = (i * 4) & 255;
    *(ushort4*)&w3sh[row * A_STRIDE + col] = *(const ushort4*)&w3h[row * 256 + col];
    *(ushort4*)&w3sl[row * A_STRIDE + col] = *(const ushort4*)&w3l[row * 256 + col];
  }

  bf16x8 b2hreg[8], b2lreg[8];
  #pragma unroll
  for (int ks = 0; ks < 8; ++ks) {
    const size_t bo = (size_t)(wv * 16 + ln) * 256 + ks * 32 + kg * 8;
    b2hreg[ks] = *(const bf16x8*)&w2h[bo];
    b2lreg[ks] = *(const bf16x8*)&w2l[bo];
  }
  const float bias2 = b2[wv * 16 + ln];
  const int mt3 = (wv >> 1) & 3, nt3 = wv & 1;
  const float b3v = b3[nt3 * 16 + ln];
  __syncthreads();

  for (int grp = blockIdx.x; grp < E_EDGES / 64; grp += gridDim.x) {
    const long long e0 = (long long)grp * 64;

    if (t < 64 * 9) rawt[(t / 9) * 12 + (t % 9)] = raw[e0 * 9 + t];
    __syncthreads();

    {
      const int col = t & 255, r0 = (t >> 8) * 16;
      const float bv = b1[col];
      float wk[9];
      #pragma unroll
      for (int k = 0; k < 9; ++k) wk[k] = W1[k * 256 + col];
      #pragma unroll
      for (int r = 0; r < 16; ++r) {
        const int row = r0 + r;
        const float4 ra = *(const float4*)&rawt[row * 12];
        const float4 rb = *(const float4*)&rawt[row * 12 + 4];
        const float rc = rawt[row * 12 + 8];
        float s = bv;
        s = fmaf(ra.x, wk[0], s); s = fmaf(ra.y, wk[1], s);
        s = fmaf(ra.z, wk[2], s); s = fmaf(ra.w, wk[3], s);
        s = fmaf(rb.x, wk[4], s); s = fmaf(rb.y, wk[5], s);
        s = fmaf(rb.z, wk[6], s); s = fmaf(rb.w, wk[7], s);
        s = fmaf(rc, wk[8], s);
        const float v = fmaxf(s, 0.f);
        const ushort h = f32_to_bf16(v);
        ah[row * A_STRIDE + col] = h;
        al[row * A_STRIDE + col] = f32_to_bf16(v - bf16_to_f32(h));
      }
    }
    __syncthreads();

    f32x4 acc[4];
    #pragma unroll
    for (int mt = 0; mt < 4; ++mt) {
      acc[mt][0] = 0.f; acc[mt][1] = 0.f; acc[mt][2] = 0.f; acc[mt][3] = 0.f;
    }
    #pragma unroll
    for (int ks = 0; ks < 8; ++ks) {
      const int ka = ks * 32 + kg * 8;
      #pragma unroll
      for (int mt = 0; mt < 4; ++mt) {
        const bf16x8 ahf = *(const bf16x8*)&ah[(mt * 16 + ln) * A_STRIDE + ka];
        const bf16x8 alf = *(const bf16x8*)&al[(mt * 16 + ln) * A_STRIDE + ka];
        acc[mt] = __builtin_amdgcn_mfma_f32_16x16x32_bf16(ahf, b2hreg[ks], acc[mt], 0, 0, 0);
        acc[mt] = __builtin_amdgcn_mfma_f32_16x16x32_bf16(alf, b2hreg[ks], acc[mt], 0, 0, 0);
        acc[mt] = __builtin_amdgcn_mfma_f32_16x16x32_bf16(ahf, b2lreg[ks], acc[mt], 0, 0, 0);
      }
    }
    __syncthreads();

    {
      const int colg = wv * 16 + ln;
      #pragma unroll
      for (int mt = 0; mt < 4; ++mt)
        #pragma unroll
        for (int r = 0; r < 4; ++r) {
          const int rowe = mt * 16 + kg * 4 + r;
          const float v = fmaxf(acc[mt][r] + bias2, 0.f);
          const ushort h = f32_to_bf16(v);
          ah[rowe * A_STRIDE + colg] = h;
          al[rowe * A_STRIDE + colg] = f32_to_bf16(v - bf16_to_f32(h));
        }
    }
    __syncthreads();

    if (wv < 8) {
      f32x4 acc3;
      acc3[0] = 0.f; acc3[1] = 0.f; acc3[2] = 0.f; acc3[3] = 0.f;
      #pragma unroll
      for (int ks = 0; ks < 8; ++ks) {
        const int ka = ks * 32 + kg * 8;
        const bf16x8 a_h = *(const bf16x8*)&ah[(mt3 * 16 + ln) * A_STRIDE + ka];
        const bf16x8 a_l = *(const bf16x8*)&al[(mt3 * 16 + ln) * A_STRIDE + ka];
        const bf16x8 b_h = *(const bf16x8*)&w3sh[(nt3 * 16 + ln) * A_STRIDE + ka];
        const bf16x8 b_l = *(const bf16x8*)&w3sl[(nt3 * 16 + ln) * A_STRIDE + ka];
        acc3 = __builtin_amdgcn_mfma_f32_16x16x32_bf16(a_h, b_h, acc3, 0, 0, 0);
        acc3 = __builtin_amdgcn_mfma_f32_16x16x32_bf16(a_l, b_h, acc3, 0, 0, 0);
        acc3 = __builtin_amdgcn_mfma_f32_16x16x32_bf16(a_h, b_l, acc3, 0, 0, 0);
      }
      const int col3 = nt3 * 16 + ln;
      #pragma unroll
      for (int r = 0; r < 4; ++r) {
        const int rowe = mt3 * 16 + kg * 4 + r;
        const float v = fmaxf(acc3[r] + b3v, 0.f);
        const ushort h = f32_to_bf16(v);
        const size_t idx = (size_t)(e0 + rowe) * 32 + col3;
        pair_h[idx] = h;
        pair_l[idx] = f32_to_bf16(v - bf16_to_f32(h));
      }
    }
    __syncthreads();
  }
}

// ========== fc1 (b=0 only): f = relu(x @ fc1_W + b); emits f32 + split ==========
__global__ __launch_bounds__(256) void fc1_kernel(
    const float* __restrict__ x, const float* __restrict__ W,
    const float* __restrict__ b, float* __restrict__ f,
    ushort* __restrict__ f_h, ushort* __restrict__ f_l)
{
  __shared__ float Wl[128 * 32];
  const int t = threadIdx.x;
  #pragma unroll
  for (int j = 0; j < 4; ++j) {
    const int off = t * 4 + j * 1024;
    *(float4*)&Wl[off] = *(const float4*)&W[off];
  }
  __syncthreads();
  const int c = t & 31, rr = t >> 5;
  const long long r = (long long)blockIdx.x * 8 + rr;
  const float* xr = x + r * 128;
  float acc = b[c];
  #pragma unroll 8
  for (int k = 0; k < 128; k += 4) {
    const float4 a = *(const float4*)&xr[k];
    acc = fmaf(a.x, Wl[(k + 0) * 32 + c], acc);
    acc = fmaf(a.y, Wl[(k + 1) * 32 + c], acc);
    acc = fmaf(a.z, Wl[(k + 2) * 32 + c], acc);
    acc = fmaf(a.w, Wl[(k + 3) * 32 + c], acc);
  }
  const float v = fmaxf(acc, 0.f);
  f[r * 32 + c] = v;
  const ushort h = f32_to_bf16(v);
  f_h[r * 32 + c] = h;
  f_l[r * 32 + c] = f32_to_bf16(v - bf16_to_f32(h));
}

// === fused edge MLP + segment-max + post MLP + residual + next-fc1 ===
// Block owns dets 32*blockIdx .. +31 (4 iters x 8 dets). m -> LDS split.
#define W1S 104
#define W2S 72
#define CTS 36
#define PXS 136

__global__ __launch_bounds__(512, 2) void edge_post_kernel(
    const ushort* __restrict__ pair_h, const ushort* __restrict__ pair_l,
    const float* __restrict__ f,
    const ushort* __restrict__ f_h, const ushort* __restrict__ f_l,
    const int* __restrict__ nIdxs,
    const float* __restrict__ W1g, const float* __restrict__ bb1,
    const ushort* __restrict__ gw1h, const ushort* __restrict__ gw1l,
    const ushort* __restrict__ gw2h, const ushort* __restrict__ gw2l,
    const float* __restrict__ bb2,
    const float* __restrict__ x,
    const ushort* __restrict__ p1h, const ushort* __restrict__ p1l,
    const float* __restrict__ pob1,
    const ushort* __restrict__ p2h, const ushort* __restrict__ p2l,
    const float* __restrict__ pob2,
    const ushort* __restrict__ oh, const ushort* __restrict__ ol,
    const float* __restrict__ outb,
    const ushort* __restrict__ fch, const ushort* __restrict__ fcl,
    const float* __restrict__ fcb, int do_fc1,
    float* __restrict__ y,
    float* __restrict__ fo, ushort* __restrict__ fo_h, ushort* __restrict__ fo_l)
{
  // carved LDS: persistent weights+m | phase region (h1 for edge, hh/yl for post)
  __shared__ __align__(16) unsigned char smem[137216];
  ushort* W1hS = (ushort*)(smem);              // 13312 B
  ushort* W1lS = (ushort*)(smem + 13312);      // 13312
  ushort* W2hS = (ushort*)(smem + 26624);      // 9216
  ushort* W2lS = (ushort*)(smem + 35840);      // 9216
  float*  W1cT = (float*)(smem + 45056);       // 9216
  ushort* msh  = (ushort*)(smem + 54272);      // 4608 (m split hi, 32 x W2S)
  ushort* msl  = (ushort*)(smem + 58880);      // 4608
  ushort* h1hB = (ushort*)(smem + 63488);      // 8 x 32*W2S = 36864 (edge)
  ushort* h1lB = (ushort*)(smem + 100352);     // 36864
  ushort* hhB  = (ushort*)(smem + 63488);      // 4608 (post, aliases h1)
  ushort* hlB  = (ushort*)(smem + 68096);      // 4608
  ushort* yhB  = (ushort*)(smem + 72704);      // 8704 (32 x PXS)
  ushort* ylB  = (ushort*)(smem + 81408);      // 8704

  const int t = threadIdx.x;
  const int lane = t & 63, wv = t >> 6;
  const int ln = lane & 15, kg = lane >> 4;
  const long long r0 = (long long)blockIdx.x * 32;

  // ---- stage edge weight tables ----
  for (int i = t; i < 1536; i += 512) {
    const int idx = i * 4, row = idx / 96, k = idx % 96;
    *(ushort4*)&W1hS[row * W1S + k] = *(const ushort4*)&gw1h[idx];
    *(ushort4*)&W1lS[row * W1S + k] = *(const ushort4*)&gw1l[idx];
  }
  for (int i = t; i < 1024; i += 512) {
    const int idx = i * 4, row = idx >> 6, k = idx & 63;
    *(ushort4*)&W2hS[row * W2S + k] = *(const ushort4*)&gw2h[idx];
    *(ushort4*)&W2lS[row * W2S + k] = *(const ushort4*)&gw2l[idx];
  }
  for (int i = t; i < 2048; i += 512) {
    const int col = i >> 5, j = i & 31;
    W1cT[col * CTS + j] = W1g[(32 + j) * 64 + col];
  }
  __syncthreads();

  ushort* h1h = h1hB + wv * 32 * W2S;
  ushort* h1l = h1lB + wv * 32 * W2S;

  // ---- edge phase: 4 iterations x 8 dets ----
  #pragma unroll 1
  for (int it = 0; it < 4; ++it) {
    const int d = (int)r0 + it * 8 + wv;
    const long long e0 = (long long)d * 32;
    const int rowt = it * 8 + wv;   // row in the block's 32-det tile

    float cfs[4];
    {
      const float4 fv0 = *(const float4*)&f[(size_t)d * 32 + kg * 8];
      const float4 fv1 = *(const float4*)&f[(size_t)d * 32 + kg * 8 + 4];
      #pragma unroll
      for (int nt = 0; nt < 4; ++nt) {
        const int col = nt * 16 + ln;
        const float4 w0 = *(const float4*)&W1cT[col * CTS + kg * 8];
        const float4 w1 = *(const float4*)&W1cT[col * CTS + kg * 8 + 4];
        float s = fv0.x * w0.x + fv0.y * w0.y + fv0.z * w0.z + fv0.w * w0.w
                + fv1.x * w1.x + fv1.y * w1.y + fv1.z * w1.z + fv1.w * w1.w;
        s += __shfl_xor(s, 16);
        s += __shfl_xor(s, 32);
        cfs[nt] = s + bb1[col];
      }
    }

    f32x4 acc1[4][2];
    #pragma unroll
    for (int nt = 0; nt < 4; ++nt)
      #pragma unroll
      for (int mt = 0; mt < 2; ++mt) {
        acc1[nt][mt][0] = 0.f; acc1[nt][mt][1] = 0.f;
        acc1[nt][mt][2] = 0.f; acc1[nt][mt][3] = 0.f;
      }
    bf16x8 ph[2], pl_[2], nh[2], nl_[2];
    #pragma unroll
    for (int mt = 0; mt < 2; ++mt) {
      const long long row = e0 + mt * 16 + ln;
      ph[mt]  = *(const bf16x8*)&pair_h[row * 32 + kg * 8];
      pl_[mt] = *(const bf16x8*)&pair_l[row * 32 + kg * 8];
      const int n = nIdxs[row];
      bf16x8 vh = *(const bf16x8*)&f_h[(size_t)n * 32 + kg * 8];
      bf16x8 vl = *(const bf16x8*)&f_l[(size_t)n * 32 + kg * 8];
      if (n == d) { vh = (bf16x8){0,0,0,0,0,0,0,0}; vl = (bf16x8){0,0,0,0,0,0,0,0}; }
      nh[mt] = vh; nl_[mt] = vl;
    }
    #pragma unroll
    for (int nt = 0; nt < 4; ++nt) {
      const int bro = (nt * 16 + ln) * W1S;
      const bf16x8 b0h = *(const bf16x8*)&W1hS[bro + kg * 8];
      const bf16x8 b0l = *(const bf16x8*)&W1lS[bro + kg * 8];
      const bf16x8 b1h = *(const bf16x8*)&W1hS[bro + 64 + kg * 8];
      const bf16x8 b1l = *(const bf16x8*)&W1lS[bro + 64 + kg * 8];
      #pragma unroll
      for (int mt = 0; mt < 2; ++mt) {
        acc1[nt][mt] = __builtin_amdgcn_mfma_f32_16x16x32_bf16(ph[mt], b0h, acc1[nt][mt], 0, 0, 0);
        acc1[nt][mt] = __builtin_amdgcn_mfma_f32_16x16x32_bf16(pl_[mt], b0h, acc1[nt][mt], 0, 0, 0);
        acc1[nt][mt] = __builtin_amdgcn_mfma_f32_16x16x32_bf16(ph[mt], b0l, acc1[nt][mt], 0, 0, 0);
        acc1[nt][mt] = __builtin_amdgcn_mfma_f32_16x16x32_bf16(nh[mt], b1h, acc1[nt][mt], 0, 0, 0);
        acc1[nt][mt] = __builtin_amdgcn_mfma_f32_16x16x32_bf16(nl_[mt], b1h, acc1[nt][mt], 0, 0, 0);
        acc1[nt][mt] = __builtin_amdgcn_mfma_f32_16x16x32_bf16(nh[mt], b1l, acc1[nt][mt], 0, 0, 0);
      }
    }

    #pragma unroll
    for (int nt = 0; nt < 4; ++nt) {
      const int col = nt * 16 + ln;
      #pragma unroll
      for (int mt = 0; mt < 2; ++mt)
        #pragma unroll
        for (int r = 0; r < 4; ++r) {
          const int row = mt * 16 + kg * 4 + r;
          const float v = fmaxf(acc1[nt][mt][r] + cfs[nt], 0.f);
          const ushort h = f32_to_bf16(v);
          h1h[row * W2S + col] = h;
          h1l[row * W2S + col] = f32_to_bf16(v - bf16_to_f32(h));
        }
    }

    f32x4 acc2[4][2];
    #pragma unroll
    for (int mt = 0; mt < 4; ++mt)
      #pragma unroll
      for (int nt = 0; nt < 2; ++nt) {
        acc2[mt][nt][0] = 0.f; acc2[mt][nt][1] = 0.f;
        acc2[mt][nt][2] = 0.f; acc2[mt][nt][3] = 0.f;
      }
    #pragma unroll
    for (int ks = 0; ks < 2; ++ks) {
      const int ka = ks * 32 + kg * 8;
      bf16x8 bh[2], bl[2];
      #pragma unroll
      for (int nt = 0; nt < 2; ++nt) {
        bh[nt] = *(const bf16x8*)&h1h[(nt * 16 + ln) * W2S + ka];
        bl[nt] = *(const bf16x8*)&h1l[(nt * 16 + ln) * W2S + ka];
      }
      #pragma unroll
      for (int mt = 0; mt < 4; ++mt) {
        const bf16x8 a_h = *(const bf16x8*)&W2hS[(mt * 16 + ln) * W2S + ka];
        const bf16x8 a_l = *(const bf16x8*)&W2lS[(mt * 16 + ln) * W2S + ka];
        #pragma unroll
        for (int nt = 0; nt < 2; ++nt) {
          acc2[mt][nt] = __builtin_amdgcn_mfma_f32_16x16x32_bf16(a_h, bh[nt], acc2[mt][nt], 0, 0, 0);
          acc2[mt][nt] = __builtin_amdgcn_mfma_f32_16x16x32_bf16(a_h, bl[nt], acc2[mt][nt], 0, 0, 0);
          acc2[mt][nt] = __builtin_amdgcn_mfma_f32_16x16x32_bf16(a_l, bh[nt], acc2[mt][nt], 0, 0, 0);
        }
      }
    }

    #pragma unroll
    for (int mt = 0; mt < 4; ++mt)
      #pragma unroll
      for (int r = 0; r < 4; ++r) {
        float mx = fmaxf(acc2[mt][0][r], acc2[mt][1][r]);
        mx = fmaxf(mx, __shfl_xor(mx, 1));
        mx = fmaxf(mx, __shfl_xor(mx, 2));
        mx = fmaxf(mx, __shfl_xor(mx, 4));
        mx = fmaxf(mx, __shfl_xor(mx, 8));
        if (ln == mt * 4 + r) {
          const int outcol = mt * 16 + kg * 4 + r;
          const float v = fmaxf(mx + bb2[outcol], 0.f);
          const ushort h = f32_to_bf16(v);
          msh[rowt * W2S + outcol] = h;
          msl[rowt * W2S + outcol] = f32_to_bf16(v - bf16_to_f32(h));
        }
      }
  }
  __syncthreads();   // m tile complete; h1 region free -> post temporaries

  // ---- post layer1: 32x64, wave -> (mt=wv>>2, nt=wv&3) ----
  {
    const int mt = wv >> 2, nt = wv & 3, col = nt * 16 + ln;
    const ushort* bh = p1h + (size_t)col * 64;
    const ushort* bl = p1l + (size_t)col * 64;
    f32x4 acc; acc[0] = 0.f; acc[1] = 0.f; acc[2] = 0.f; acc[3] = 0.f;
    #pragma unroll
    for (int ks = 0; ks < 2; ++ks) {
      const int ka = ks * 32 + kg * 8;
      const bf16x8 a_h = *(const bf16x8*)&msh[(mt * 16 + ln) * W2S + ka];
      const bf16x8 a_l = *(const bf16x8*)&msl[(mt * 16 + ln) * W2S + ka];
      const bf16x8 b_h = *(const bf16x8*)&bh[ka];
      const bf16x8 b_l = *(const bf16x8*)&bl[ka];
      acc = __builtin_amdgcn_mfma_f32_16x16x32_bf16(a_h, b_h, acc, 0, 0, 0);
      acc = __builtin_amdgcn_mfma_f32_16x16x32_bf16(a_l, b_h, acc, 0, 0, 0);
      acc = __builtin_amdgcn_mfma_f32_16x16x32_bf16(a_h, b_l, acc, 0, 0, 0);
    }
    const float bias = pob1[col];
    #pragma unroll
    for (int r = 0; r < 4; ++r) {
      const int row = mt * 16 + kg * 4 + r;
      const float v = fmaxf(acc[r] + bias, 0.f);
      const ushort h = f32_to_bf16(v);
      hhB[row * W2S + col] = h;
      hlB[row * W2S + col] = f32_to_bf16(v - bf16_to_f32(h));
    }
  }
  __syncthreads();

  // ---- post layer2: reads h1(post), writes h2 into msh/msl ----
  {
    const int mt = wv >> 2, nt = wv & 3, col = nt * 16 + ln;
    const ushort* bh = p2h + (size_t)col * 64;
    const ushort* bl = p2l + (size_t)col * 64;
    f32x4 acc; acc[0] = 0.f; acc[1] = 0.f; acc[2] = 0.f; acc[3] = 0.f;
    #pragma unroll
    for (int ks = 0; ks < 2; ++ks) {
      const int ka = ks * 32 + kg * 8;
      const bf16x8 a_h = *(const bf16x8*)&hhB[(mt * 16 + ln) * W2S + ka];
      const bf16x8 a_l = *(const bf16x8*)&hlB[(mt * 16 + ln) * W2S + ka];
      const bf16x8 b_h = *(const bf16x8*)&bh[ka];
      const bf16x8 b_l = *(const bf16x8*)&bl[ka];
      acc = __builtin_amdgcn_mfma_f32_16x16x32_bf16(a_h, b_h, acc, 0, 0, 0);
      acc = __builtin_amdgcn_mfma_f32_16x16x32_bf16(a_l, b_h, acc, 0, 0, 0);
      acc = __builtin_amdgcn_mfma_f32_16x16x32_bf16(a_h, b_l, acc, 0, 0, 0);
    }
    const float bias = pob2[col];
    __syncthreads();   // all layer-1 reads of msh done before overwrite
    #pragma unroll
    for (int r = 0; r < 4; ++r) {
      const int row = mt * 16 + kg * 4 + r;
      const float v = fmaxf(acc[r] + bias, 0.f);
      const ushort h = f32_to_bf16(v);
      msh[row * W2S + col] = h;
      msl[row * W2S + col] = f32_to_bf16(v - bf16_to_f32(h));
    }
  }
  __syncthreads();

  // ---- post layer3: 32x128 + residual; wave owns cols wv*16..+16 ----
  {
    const int col = wv * 16 + ln;
    const ushort* bh = oh + (size_t)col * 64;
    const ushort* bl = ol + (size_t)col * 64;
    f32x4 acc[2];
    #pragma unroll
    for (int mt = 0; mt < 2; ++mt) {
      acc[mt][0] = 0.f; acc[mt][1] = 0.f; acc[mt][2] = 0.f; acc[mt][3] = 0.f;
    }
    #pragma unroll
    for (int ks = 0; ks < 2; ++ks) {
      const int ka = ks * 32 + kg * 8;
      const bf16x8 b_h = *(const bf16x8*)&bh[ka];
      const bf16x8 b_l = *(const bf16x8*)&bl[ka];
      #pragma unroll
      for (int mt = 0; mt < 2; ++mt) {
        const bf16x8 a_h = *(const bf16x8*)&msh[(mt * 16 + ln) * W2S + ka];
        const bf16x8 a_l = *(const bf16x8*)&msl[(mt * 16 + ln) * W2S + ka];
        acc[mt] = __builtin_amdgcn_mfma_f32_16x16x32_bf16(a_h, b_h, acc[mt], 0, 0, 0);
        acc[mt] = __builtin_amdgcn_mfma_f32_16x16x32_bf16(a_l, b_h, acc[mt], 0, 0, 0);
        acc[mt] = __builtin_amdgcn_mfma_f32_16x16x32_bf16(a_h, b_l, acc[mt], 0, 0, 0);
      }
    }
    const float bias = outb[col];
    #pragma unroll
    for (int mt = 0; mt < 2; ++mt)
      #pragma unroll
      for (int r = 0; r < 4; ++r) {
        const int row = mt * 16 + kg * 4 + r;
        const size_t idx = (size_t)(r0 + row) * 128 + col;
        const float v = fmaxf(x[idx] + acc[mt][r] + bias, 0.f);
        y[idx] = v;
        const ushort h = f32_to_bf16(v);
        yhB[row * PXS + col] = h;
        ylB[row * PXS + col] = f32_to_bf16(v - bf16_to_f32(h));
      }
  }
  __syncthreads();

  // ---- fused fc1 for next block: 32x32, K=128; waves 0-3 ----
  if (do_fc1 && wv < 4) {
    const int mt = wv >> 1, nt = wv & 1, col = nt * 16 + ln;
    const ushort* bh = fch + (size_t)col * 128;
    const ushort* bl = fcl + (size_t)col * 128;
    f32x4 acc; acc[0] = 0.f; acc[1] = 0.f; acc[2] = 0.f; acc[3] = 0.f;
    #pragma unroll
    for (int ks = 0; ks < 4; ++ks) {
      const int ka = ks * 32 + kg * 8;
      const bf16x8 a_h = *(const bf16x8*)&yhB[(mt * 16 + ln) * PXS + ka];
      const bf16x8 a_l = *(const bf16x8*)&ylB[(mt * 16 + ln) * PXS + ka];
      const bf16x8 b_h = *(const bf16x8*)&bh[ka];
      const bf16x8 b_l = *(const bf16x8*)&bl[ka];
      acc = __builtin_amdgcn_mfma_f32_16x16x32_bf16(a_h, b_h, acc, 0, 0, 0);
      acc = __builtin_amdgcn_mfma_f32_16x16x32_bf16(a_l, b_h, acc, 0, 0, 0);
      acc = __builtin_amdgcn_mfma_f32_16x16x32_bf16(a_h, b_l, acc, 0, 0, 0);
    }
    const float bias = fcb[col];
    #pragma unroll
    for (int r = 0; r < 4; ++r) {
      const int row = mt * 16 + kg * 4 + r;
      const float v = fmaxf(acc[r] + bias, 0.f);
      const size_t idx = (size_t)(r0 + row) * 32 + col;
      fo[idx] = v;
      const ushort h = f32_to_bf16(v);
      fo_h[idx] = h;
      fo_l[idx] = f32_to_bf16(v - bf16_to_f32(h));
    }
  }
}

// ====== score head: 3x (128->128 relu) + dot, split-bf16 MFMA, 32 rows/block ======
#define XS 136

__global__ __launch_bounds__(512) void score_head_kernel(
    const float* __restrict__ x,
    const ushort* __restrict__ swh, const ushort* __restrict__ swl,
    const float* __restrict__ sb,
    const float* __restrict__ pW, const float* __restrict__ pb,
    float* __restrict__ out)
{
  __shared__ __align__(16) ushort xh[2][32 * XS], xl[2][32 * XS];
  __shared__ __align__(16) float hsf[32 * XS];
  __shared__ float pWs[128];
  const int t = threadIdx.x;
  const int lane = t & 63, wv = t >> 6;
  const int ln = lane & 15, kg = lane >> 4;
  const long long r0 = (long long)blockIdx.x * 32;

  if (t < 128) pWs[t] = pW[t];
  for (int i = t; i < 32 * 32; i += 512) {
    const int row = i >> 5, cq = (i & 31) * 4;
    const float4 v4 = *(const float4*)&x[(r0 + row) * 128 + cq];
    const float vv[4] = {v4.x, v4.y, v4.z, v4.w};
    #pragma unroll
    for (int j = 0; j < 4; ++j) {
      const ushort h = f32_to_bf16(vv[j]);
      xh[0][row * XS + cq + j] = h;
      xl[0][row * XS + cq + j] = f32_to_bf16(vv[j] - bf16_to_f32(h));
    }
  }
  __syncthreads();

  const int colg = wv * 16 + ln;
  int cur = 0;
  #pragma unroll 1
  for (int layer = 0; layer < 3; ++layer) {
    const ushort* wh = swh + (size_t)layer * 16384 + (size_t)colg * 128;
    const ushort* wl = swl + (size_t)layer * 16384 + (size_t)colg * 128;
    f32x4 acc[2];
    #pragma unroll
    for (int mt = 0; mt < 2; ++mt) {
      acc[mt][0] = 0.f; acc[mt][1] = 0.f; acc[mt][2] = 0.f; acc[mt][3] = 0.f;
    }
    #pragma unroll
    for (int ks = 0; ks < 4; ++ks) {
      const int ka = ks * 32 + kg * 8;
      const bf16x8 b_h = *(const bf16x8*)&wh[ka];
      const bf16x8 b_l = *(const bf16x8*)&wl[ka];
      #pragma unroll
      for (int mt = 0; mt < 2; ++mt) {
        const bf16x8 a_h = *(const bf16x8*)&xh[cur][(mt * 16 + ln) * XS + ka];
        const bf16x8 a_l = *(const bf16x8*)&xl[cur][(mt * 16 + ln) * XS + ka];
        acc[mt] = __builtin_amdgcn_mfma_f32_16x16x32_bf16(a_h, b_h, acc[mt], 0, 0, 0);
        acc[mt] = __builtin_amdgcn_mfma_f32_16x16x32_bf16(a_l, b_h, acc[mt], 0, 0, 0);
        acc[mt] = __builtin_amdgcn_mfma_f32_16x16x32_bf16(a_h, b_l, acc[mt], 0, 0, 0);
      }
    }
    const float bias = sb[layer * 128 + colg];
    __syncthreads();
    if (layer < 2) {
      #pragma unroll
      for (int mt = 0; mt < 2; ++mt)
        #pragma unroll
        for (int r = 0; r < 4; ++r) {
          const int row = mt * 16 + kg * 4 + r;
          const float v = fmaxf(acc[mt][r] + bias, 0.f);
          const ushort h = f32_to_bf16(v);
          xh[cur ^ 1][row * XS + colg] = h;
          xl[cur ^ 1][row * XS + colg] = f32_to_bf16(v - bf16_to_f32(h));
        }
      cur ^= 1;
    } else {
      #pragma unroll
      for (int mt = 0; mt < 2; ++mt)
        #pragma unroll
        for (int r = 0; r < 4; ++r) {
          const int row = mt * 16 + kg * 4 + r;
          hsf[row * XS + colg] = fmaxf(acc[mt][r] + bias, 0.f);
        }
    }
    __syncthreads();
  }

  {
    const int row = t >> 4, l16 = t & 15;
    const float4 a0 = *(const float4*)&hsf[row * XS + l16 * 8];
    const float4 a1 = *(const float4*)&hsf[row * XS + l16 * 8 + 4];
    const float4 w0 = *(const float4*)&pWs[l16 * 8];
    const float4 w1 = *(const float4*)&pWs[l16 * 8 + 4];
    float s = a0.x * w0.x + a0.y * w0.y + a0.z * w0.z + a0.w * w0.w
            + a1.x * w1.x + a1.y * w1.y + a1.z * w1.z + a1.w * w1.w;
    s += __shfl_xor(s, 1);
    s += __shfl_xor(s, 2);
    s += __shfl_xor(s, 4);
    s += __shfl_xor(s, 8);
    if (l16 == 0) out[r0 + row] = s + pb[0];
  }
}

extern "C" void kernel_launch(void* const* d_in, const int* in_sizes, int n_in,
                              void* d_out, int out_size, void* d_ws, size_t ws_size,
                              hipStream_t stream)
{
  const float* detF    = (const float*)d_in[0];
  const float* pairRaw = (const float*)d_in[1];
  const int*   cIdx    = (const int*)d_in[2];
  const int*   nIdx    = (const int*)d_in[3];
  const float* gW1 = (const float*)d_in[4];   const float* gb1 = (const float*)d_in[5];
  const float* gW2 = (const float*)d_in[6];   const float* gb2 = (const float*)d_in[7];
  const float* gW3 = (const float*)d_in[8];   const float* gb3 = (const float*)d_in[9];
  const float* fc1W = (const float*)d_in[10]; const float* fc1b = (const float*)d_in[11];
  const float* pwW1 = (const float*)d_in[12]; const float* pwb1 = (const float*)d_in[13];
  const float* pwW2 = (const float*)d_in[14]; const float* pwb2 = (const float*)d_in[15];
  const float* poW1 = (const float*)d_in[16]; const float* pob1 = (const float*)d_in[17];
  const float* poW2 = (const float*)d_in[18]; const float* pob2 = (const float*)d_in[19];
  const float* outW = (const float*)d_in[20]; const float* outb = (const float*)d_in[21];
  const float* sW = (const float*)d_in[22];   const float* sb = (const float*)d_in[23];
  const float* predW = (const float*)d_in[24]; const float* predb = (const float*)d_in[25];
  float* out = (float*)d_out;
  (void)cIdx;   // cIdxs == repeat(arange(N), DEG) per setup; d = e >> 5

  ushort* w2h  = (ushort*)d_ws;
  ushort* w2l  = w2h + 65536;
  ushort* w3h  = w2l + 65536;
  ushort* w3l  = w3h + 8192;
  ushort* w1eh = w3l + 8192;
  ushort* w1el = w1eh + 24576;
  ushort* w2eh = w1el + 24576;
  ushort* w2el = w2eh + 16384;
  ushort* swh  = w2el + 16384;                 // 3*16384
  ushort* swl  = swh + 49152;
  ushort* p1h  = swl + 49152;                  // 4*4096
  ushort* p1l  = p1h + 16384;
  ushort* p2h  = p1l + 16384;
  ushort* p2l  = p2h + 16384;
  ushort* ohh  = p2l + 16384;                  // 4*8192
  ushort* ohl  = ohh + 32768;
  ushort* fth  = ohl + 32768;                  // 4*4096
  ushort* ftl  = fth + 16384;
  ushort* pair_h = ftl + 16384;
  ushort* pair_l = pair_h + (size_t)E_EDGES * 32;
  ushort* fA_h   = pair_l + (size_t)E_EDGES * 32;
  ushort* fA_l   = fA_h + (size_t)N_DETS * 32;
  ushort* fB_h   = fA_l + (size_t)N_DETS * 32;
  ushort* fB_l   = fB_h + (size_t)N_DETS * 32;
  float* fA = (float*)(fB_l + (size_t)N_DETS * 32);
  float* fB = fA + (size_t)N_DETS * 32;
  float* xa = fB + (size_t)N_DETS * 32;
  float* xb = xa + (size_t)N_DETS * 128;

  hipMemcpyAsync(xa, detF, (size_t)N_DETS * 128 * sizeof(float),
                 hipMemcpyDeviceToDevice, stream);

  split_w_kernel<<<256, 256, 0, stream>>>(gW2, w2h, w2l, 256);
  split_w_kernel<<<32, 256, 0, stream>>>(gW3, w3h, w3l, 32);
  split_edge_w_kernel<<<4, 256, 0, stream>>>(pwW1, pwW2, w1eh, w1el, w2eh, w2el);
  split_score_w_kernel<<<384, 128, 0, stream>>>(sW, swh, swl);
  split_post_w_kernel<<<4, 256, 0, stream>>>(poW1, poW2, outW, fc1W,
      p1h, p1l, p2h, p2l, ohh, ohl, fth, ftl);

  pair_mlp_kernel<<<256, 1024, 0, stream>>>(pairRaw, gW1, gb1,
      w2h, w2l, gb2, w3h, w3l, gb3, pair_h, pair_l);

  // b=0 fc1 standalone
  fc1_kernel<<<N_DETS / 8, 256, 0, stream>>>(xa, fc1W, fc1b, fA, fA_h, fA_l);

  float* xin = xa;
  float* xout = xb;
  float* fin = fA;  ushort* finh = fA_h;  ushort* finl = fA_l;
  float* fo  = fB;  ushort* foh  = fB_h;  ushort* fol  = fB_l;
  for (int b = 0; b < 4; ++b) {
    const int nb = (b + 1) & 3;
    edge_post_kernel<<<N_DETS / 32, 512, 0, stream>>>(pair_h, pair_l,
        fin, finh, finl, nIdx,
        pwW1 + b * 6144, pwb1 + b * 64,
        w1eh + b * 6144, w1el + b * 6144, w2eh + b * 4096, w2el + b * 4096,
        pwb2 + b * 64,
        xin,
        p1h + b * 4096, p1l + b * 4096, pob1 + b * 64,
        p2h + b * 4096, p2l + b * 4096, pob2 + b * 64,
        ohh + b * 8192, ohl + b * 8192, outb + b * 128,
        fth + nb * 4096, ftl + nb * 4096, fc1b + nb * 32, (b < 3) ? 1 : 0,
        xout, fo, foh, fol);
    float* tmp = xout; xout = xin; xin = tmp;
    float* tf = fo; fo = fin; fin = tf;
    ushort* th = foh; foh = finh; finh = th;
    ushort* tl = fol; fol = finl; finl = tl;
  }
  score_head_kernel<<<N_DETS / 32, 512, 0, stream>>>(xin, swh, swl, sb,
      predW, predb, out);
}